// Round 11
// baseline (276.143 us; speedup 1.0000x reference)
//
#include <hip/hip_runtime.h>
#include <stdint.h>

#define B 64
#define N 784
#define C 512
#define M 256

typedef unsigned long long u64;
typedef unsigned short u16;
typedef unsigned char u8;
typedef long i64;
typedef __attribute__((ext_vector_type(8))) short short8;
typedef __attribute__((ext_vector_type(4))) float f32x4;

static __device__ __forceinline__ u64 umin64(u64 a, u64 b) { return a < b ? a : b; }

static __device__ __forceinline__ u16 f2bf(float x) {   // RNE fp32 -> bf16
    unsigned u = __float_as_uint(x);
    return (u16)((u + 0x7FFFu + ((u >> 16) & 1u)) >> 16);
}
static __device__ __forceinline__ float b2f(u16 v) {
    return __uint_as_float((unsigned)v << 16);
}

static __device__ __forceinline__ void gload_lds16(const u16* g, u16* l) {
    __builtin_amdgcn_global_load_lds((const __attribute__((address_space(1))) void*)g,
                                     (__attribute__((address_space(3))) void*)l, 16, 0, 0);
}
static __device__ __forceinline__ void gload_lds16b(const u8* g, u8* l) {
    __builtin_amdgcn_global_load_lds((const __attribute__((address_space(1))) void*)g,
                                     (__attribute__((address_space(3))) void*)l, 16, 0, 0);
}

// ---------------------------------------------------------------------------
// fused rowkey init (dirs 0,1) + fp32->bf16 convert (+ optional fp8 e4m3
// shadow copy for the vicreg gather) + row |x|^2 norms.
// ---------------------------------------------------------------------------
__global__ __launch_bounds__(256) void convnorm_kernel(
    const float* __restrict__ m1, const float* __restrict__ m2,
    u16* __restrict__ abf, u16* __restrict__ bbf,
    u8* __restrict__ a8, u8* __restrict__ b8,
    float* __restrict__ nrm, u64* __restrict__ rowkey, int do8) {
    int gid = blockIdx.x * 256 + threadIdx.x;
    if (gid < 2 * B * N) rowkey[gid] = ~0ull;      // dirs 0,1 keys
    int w = blockIdx.x * 4 + (threadIdx.x >> 6);
    int lane = threadIdx.x & 63;
    if (w >= 2 * B * N) return;
    const float* src = (w < B * N) ? m1 : m2;
    u16* dst = (w < B * N) ? abf : bbf;
    u8* dst8 = (w < B * N) ? a8 : b8;
    int row = (w < B * N) ? w : w - B * N;
    const float4* p = (const float4*)(src + (size_t)row * C);
    u64* q = (u64*)(dst + (size_t)row * C);
    unsigned* q8 = (unsigned*)(dst8 + (size_t)row * C);
    float s = 0.f;
#pragma unroll
    for (int i = 0; i < 2; ++i) {
        int idx = lane + i * 64;
        float4 v = p[idx];
        s += v.x * v.x + v.y * v.y + v.z * v.z + v.w * v.w;
        q[idx] = (u64)f2bf(v.x) | ((u64)f2bf(v.y) << 16) |
                 ((u64)f2bf(v.z) << 32) | ((u64)f2bf(v.w) << 48);
        if (do8) {
            int pk = __builtin_amdgcn_cvt_pk_fp8_f32(v.x, v.y, 0, false);
            pk = __builtin_amdgcn_cvt_pk_fp8_f32(v.z, v.w, pk, true);
            q8[idx] = (unsigned)pk;
        }
    }
#pragma unroll
    for (int off = 32; off > 0; off >>= 1) s += __shfl_down(s, off, 64);
    if (lane == 0) nrm[w] = s;
}

// ---------------------------------------------------------------------------
// MFMA feature-distance (R9 version, passing): counted-vmcnt dbuf + hoisted
// ds_read addresses. 128x128 tile, BK=64, 4 waves (2x2).
// ---------------------------------------------------------------------------
__global__ __launch_bounds__(256, 2) void feat_mfma_kernel(
    const u16* __restrict__ abf, const u16* __restrict__ bbf,
    const float* __restrict__ nrm, u64* __restrict__ rowkey) {
    int id = blockIdx.x;
    int xcd = id & 7;
    int q = id >> 3;
    int hi = q / 49, t49 = q - hi * 49;
    int b = hi * 8 + xcd;
    int tn = t49 / 7, tm = t49 - tn * 7;

    const int t = threadIdx.x;
    const int lane = t & 63, wv = t >> 6;
    const int wr = wv >> 1, wc = wv & 1;

    __shared__ __align__(16) unsigned char RAW[65536];
    __shared__ float sNa[128], sNb[128];

    const int row0 = tn * 128, col0 = tm * 128;
    if (t < 128) {
        int n = row0 + t;
        sNa[t] = (n < N) ? nrm[b * N + n] : __builtin_inff();
    } else {
        int m = col0 + (t - 128);
        sNb[t - 128] = (m < N) ? nrm[B * N + b * N + m] : __builtin_inff();
    }

    size_t aofs[4], bofs[4];
    int ldso[4];
#pragma unroll
    for (int s = 0; s < 4; ++s) {
        int c = (wv * 4 + s) * 64 + lane;
        int rl = c >> 3;
        int grp = (c & 7) ^ (rl & 7);
        int ga = row0 + rl; if (ga > N - 1) ga = N - 1;
        int gb = col0 + rl; if (gb > N - 1) gb = N - 1;
        aofs[s] = ((size_t)b * N + ga) * C + grp * 8;
        bofs[s] = ((size_t)b * N + gb) * C + grp * 8;
        ldso[s] = (wv * 4 + s) * 512;
    }

    const int l15 = lane & 15;
    const int sA_base = (wr * 64 + l15) * 64;
    const int sB_base = (wc * 64 + l15) * 64;
    const int swz0 = (((lane >> 4) + 0) ^ (l15 & 7)) << 3;
    const int swz1 = (((lane >> 4) + 4) ^ (l15 & 7)) << 3;

    f32x4 acc[4][4];
#pragma unroll
    for (int i = 0; i < 4; ++i)
#pragma unroll
        for (int j = 0; j < 4; ++j) acc[i][j] = (f32x4){0.f, 0.f, 0.f, 0.f};

    {
        u16* A0 = (u16*)RAW;
        u16* B0 = A0 + 8192;
#pragma unroll
        for (int s = 0; s < 4; ++s) {
            gload_lds16(abf + aofs[s], &A0[ldso[s]]);
            gload_lds16(bbf + bofs[s], &B0[ldso[s]]);
        }
    }

    for (int kt = 0; kt < 8; ++kt) {
        const int cur = kt & 1;
        if (kt < 7) {
            int ke = (kt + 1) * 64;
            u16* An = (u16*)(RAW + (cur ^ 1) * 32768);
            u16* Bn = An + 8192;
#pragma unroll
            for (int s = 0; s < 4; ++s) {
                gload_lds16(abf + aofs[s] + ke, &An[ldso[s]]);
                gload_lds16(bbf + bofs[s] + ke, &Bn[ldso[s]]);
            }
            asm volatile("s_waitcnt vmcnt(8)" ::: "memory");
        } else {
            asm volatile("s_waitcnt vmcnt(0)" ::: "memory");
        }
        __builtin_amdgcn_s_barrier();

        const u16* Als = (const u16*)(RAW + cur * 32768);
        const u16* Bls = Als + 8192;
        const u16* pA0 = Als + sA_base + swz0;
        const u16* pA1 = Als + sA_base + swz1;
        const u16* pB0 = Bls + sB_base + swz0;
        const u16* pB1 = Bls + sB_base + swz1;
#pragma unroll
        for (int ks = 0; ks < 2; ++ks) {
            const u16* pA = ks ? pA1 : pA0;
            const u16* pB = ks ? pB1 : pB0;
            short8 afr[4], bfr[4];
#pragma unroll
            for (int f = 0; f < 4; ++f) {
                afr[f] = *(const short8*)(pA + f * 1024);
                bfr[f] = *(const short8*)(pB + f * 1024);
            }
#pragma unroll
            for (int fi = 0; fi < 4; ++fi)
#pragma unroll
                for (int fj = 0; fj < 4; ++fj)
                    acc[fi][fj] = __builtin_amdgcn_mfma_f32_16x16x32_bf16(
                        afr[fi], bfr[fj], acc[fi][fj], 0, 0, 0);
        }
        asm volatile("s_waitcnt lgkmcnt(0)" ::: "memory");
        __builtin_amdgcn_s_barrier();
    }

    const int g4 = (lane >> 4) << 2;
    float na4[4][4], nb4[4];
#pragma unroll
    for (int fi = 0; fi < 4; ++fi) {
        float4 v = *(const float4*)&sNa[wr * 64 + fi * 16 + g4];
        na4[fi][0] = v.x; na4[fi][1] = v.y; na4[fi][2] = v.z; na4[fi][3] = v.w;
    }
#pragma unroll
    for (int fj = 0; fj < 4; ++fj) nb4[fj] = sNb[wc * 64 + fj * 16 + l15];

    u64(*red)[33] = (u64(*)[33])RAW;
    u64 ck[4] = {~0ull, ~0ull, ~0ull, ~0ull};
#pragma unroll
    for (int fi = 0; fi < 4; ++fi) {
        int rl = wr * 64 + fi * 16 + g4;
        u64 rk[4] = {~0ull, ~0ull, ~0ull, ~0ull};
#pragma unroll
        for (int fj = 0; fj < 4; ++fj) {
            unsigned colidx = (unsigned)(col0 + wc * 64 + fj * 16 + l15);
#pragma unroll
            for (int reg = 0; reg < 4; ++reg) {
                float d2 = fmaxf(na4[fi][reg] + nb4[fj] - 2.f * acc[fi][fj][reg], 0.f);
                u64 hv = ((u64)__float_as_uint(d2) << 32);
                rk[reg] = umin64(rk[reg], hv | colidx);
                ck[fj] = umin64(ck[fj], hv | (unsigned)(row0 + rl + reg));
            }
        }
#pragma unroll
        for (int reg = 0; reg < 4; ++reg)
            red[rl + reg][(wc << 4) | l15] = rk[reg];
    }
#pragma unroll
    for (int fj = 0; fj < 4; ++fj) {
        u64 best = ck[fj];
        best = umin64(best, __shfl_xor(best, 16, 64));
        best = umin64(best, __shfl_xor(best, 32, 64));
        if (lane < 16) {
            int m = col0 + wc * 64 + fj * 16 + lane;
            if (m < N) atomicMin(&rowkey[(size_t)B * N + (size_t)b * N + m], best);
        }
    }
    __syncthreads();
    if (t < 128) {
        u64 best = red[t][0];
#pragma unroll
        for (int x = 1; x < 32; ++x) best = umin64(best, red[t][x]);
        int n = row0 + t;
        if (n < N) atomicMin(&rowkey[(size_t)b * N + n], best);
    }
}

// ---------------------------------------------------------------------------
// Location-space distances (C=2): dirs 2 and 3.
// ---------------------------------------------------------------------------
__global__ __launch_bounds__(256) void loc_dist_kernel(
    const float* __restrict__ l1, const float* __restrict__ l2,
    u64* __restrict__ rowkey) {
    const int dir = blockIdx.z;
    const int b = blockIdx.y;
    const int t = threadIdx.x;
    const int n = blockIdx.x * 256 + t;
    __shared__ __align__(16) float4 s4[N];
    const float* Ap = dir ? l2 : l1;
    const float* Bp = dir ? l1 : l2;
    for (int i = t; i < N; i += 256) {
        float2 qv = ((const float2*)Bp)[b * N + i];
        s4[i] = make_float4(qv.x, qv.y, qv.x * qv.x + qv.y * qv.y, 0.f);
    }
    __syncthreads();
    if (n >= N) return;
    float2 a = ((const float2*)Ap)[b * N + n];
    float a2 = a.x * a.x + a.y * a.y;
    float nax = -2.f * a.x, nay = -2.f * a.y;
    u64 best = ~0ull;
#pragma unroll 4
    for (int mm = 0; mm < N; ++mm) {
        float4 v = s4[mm];
        float d2 = fmaxf(fmaf(nax, v.x, fmaf(nay, v.y, a2 + v.z)), 0.f);
        u64 kv = ((u64)__float_as_uint(d2) << 32) | (unsigned)mm;
        best = kv < best ? kv : best;
    }
    rowkey[(size_t)(2 + dir) * B * N + (size_t)b * N + n] = best;
}

// ---------------------------------------------------------------------------
// Per (dir, b): 256 rows with smallest NN-dist, stable, original order.
// Block (0,0) zero-inits loss accumulators + completion counter.
// ---------------------------------------------------------------------------
__global__ __launch_bounds__(256) void select_kernel(
    const u64* __restrict__ rowkey, int* __restrict__ sel_idx,
    int* __restrict__ nn_idx, float* __restrict__ acc) {
    const int b = blockIdx.x;
    const int dir = blockIdx.y;
    const int t = threadIdx.x;
    if (b == 0 && dir == 0 && t < 8) acc[t] = 0.f;
    __shared__ u64 sk[1024];
    const u64* rk = rowkey + (size_t)dir * B * N + (size_t)b * N;
    for (int i = t; i < 1024; i += 256)
        sk[i] = (i < N) ? ((rk[i] & 0xFFFFFFFF00000000ull) | (unsigned)i) : ~0ull;
    __syncthreads();
    for (unsigned k = 2; k <= 1024; k <<= 1) {
        for (unsigned j = k >> 1; j > 0; j >>= 1) {
            for (unsigned i = t; i < 1024; i += 256) {
                unsigned ixj = i ^ j;
                if (ixj > i) {
                    u64 x = sk[i], y = sk[ixj];
                    bool up = ((i & k) == 0);
                    if ((x > y) == up) { sk[i] = y; sk[ixj] = x; }
                }
            }
            __syncthreads();
        }
    }
    unsigned myidx = (unsigned)(sk[t] & 0xFFFFFFFFull);
    __syncthreads();
    unsigned* si = (unsigned*)sk;
    si[t] = myidx;
    __syncthreads();
    for (unsigned k = 2; k <= 256; k <<= 1) {
        for (unsigned j = k >> 1; j > 0; j >>= 1) {
            unsigned i = t, ixj = i ^ j;
            if (ixj > i) {
                unsigned x = si[i], y = si[ixj];
                bool up = ((i & k) == 0);
                if ((x > y) == up) { si[i] = y; si[ixj] = x; }
            }
            __syncthreads();
        }
    }
    int sel = (int)si[t];
    sel_idx[((size_t)dir * B + b) * M + t] = sel;
    nn_idx[((size_t)dir * B + b) * M + t] = (int)(unsigned)(rk[sel] & 0xFFFFFFFFull);
}

// ---------------------------------------------------------------------------
// fp8 VICReg per (pair p, location mloc): HALF the gather bytes (the measured
// limiter: 62MB compulsory HBM misses at random-granule ~640GB/s).
// 4 waves, 4 chunks (128 cols = 128B each) resident: X 32KB + Y 32KB +
// colpart 8KB = 73KB -> 2 blocks/CU. Grams via mfma_f32_16x16x32_fp8_fp8
// (identical A/B lane addressing => any within-k permutation cancels).
// 16B-granule XOR swizzle g^=(row&7) on both source and reads (rule 21).
// Fused finalize via completion counter acc[6].
// ---------------------------------------------------------------------------
__global__ __launch_bounds__(256, 2) void vicreg_fp8_kernel(
    const u8* __restrict__ a8, const u8* __restrict__ b8,
    const int* __restrict__ sel_idx, const int* __restrict__ nn_idx,
    float* __restrict__ acc, float* __restrict__ outp) {
    const int mloc = blockIdx.x;
    const int p = blockIdx.y;
    const int t = threadIdx.x;
    const int l = t & 63, w = t >> 6;

    __shared__ __align__(16) u8 X8[4][64 * 128];    // 32 KB
    __shared__ __align__(16) u8 Y8[4][64 * 128];    // 32 KB
    __shared__ float colpart[4][4][128];            // [wave][stat][col] 8 KB
    __shared__ float Rsx[64], Rsy[64];
    __shared__ int xi[64], yi[64];
    __shared__ float redsc[4][4];

    if (t < 64) xi[t] = sel_idx[((size_t)p * B + t) * M + mloc];
    else if (t < 128) yi[t - 64] = nn_idx[((size_t)p * B + (t - 64)) * M + mloc];
    __syncthreads();

    const u8* Xg = (p & 1) ? b8 : a8;
    const u8* Yg = (p & 1) ? a8 : b8;
    size_t xofs[2], yofs[2];
    int ldst[2];
#pragma unroll
    for (int s = 0; s < 2; ++s) {
        int r = w * 16 + s * 8 + (l >> 3);           // local row = batch index
        int sg = (l & 7) ^ (r & 7);                  // pre-swizzled src granule
        xofs[s] = ((size_t)(r * N + xi[r])) * C + sg * 16;
        yofs[s] = ((size_t)(r * N + yi[r])) * C + sg * 16;
        ldst[s] = (w * 16 + s * 8) * 128;
    }

    // stage all 4 chunks (16 gload/wave), drain once
#pragma unroll
    for (int kc = 0; kc < 4; ++kc)
#pragma unroll
        for (int s = 0; s < 2; ++s) {
            gload_lds16b(Xg + xofs[s] + kc * 128, &X8[kc][ldst[s]]);
            gload_lds16b(Yg + yofs[s] + kc * 128, &Y8[kc][ldst[s]]);
        }
    __syncthreads();

    f32x4 Gx[4], Gy[4], Z;
#pragma unroll
    for (int j = 0; j < 4; ++j) { Gx[j] = (f32x4){0,0,0,0}; Gy[j] = (f32x4){0,0,0,0}; }
    Z = (f32x4){0, 0, 0, 0};
    float stdacc = 0.f, covdacc = 0.f, reprp = 0.f;

#pragma unroll
    for (int kc = 0; kc < 4; ++kc) {
        const u8* Xc = X8[kc];
        const u8* Yc = Y8[kc];

        // ---- MFMA Grams: 4 K=32 steps cover this 128-col chunk ----
#pragma unroll
        for (int ks = 0; ks < 4; ++ks) {
            int g = (ks << 1) + ((l >> 4) >> 1);
            int wi = ((l >> 4) & 1) << 3;
            int soff = ((g ^ (l & 7)) << 4) + wi;    // row&7 == l&7 for all frags
            int ra = (w << 4) + (l & 15);
            i64 ax = *(const i64*)&Xc[ra * 128 + soff];
            i64 ay = *(const i64*)&Yc[ra * 128 + soff];
            i64 bx[4], by[4];
#pragma unroll
            for (int j = 0; j < 4; ++j) {
                int rb = (j << 4) + (l & 15);
                bx[j] = *(const i64*)&Xc[rb * 128 + soff];
                by[j] = *(const i64*)&Yc[rb * 128 + soff];
            }
#pragma unroll
            for (int j = 0; j < 4; ++j) {
                Gx[j] = __builtin_amdgcn_mfma_f32_16x16x32_fp8_fp8(ax, bx[j], Gx[j], 0, 0, 0);
                Gy[j] = __builtin_amdgcn_mfma_f32_16x16x32_fp8_fp8(ay, by[j], Gy[j], 0, 0, 0);
            }
            Z = __builtin_amdgcn_mfma_f32_16x16x32_fp8_fp8(ax, ay, Z, 0, 0, 0);
        }

        // ---- column stats: 4 cols/thread (bytes), 8 rows, fp32 accum ----
        {
            int c4 = (l & 31) << 2;
            int g2 = (w << 1) + (l >> 5);
            float s1x0 = 0, s1x1 = 0, s1x2 = 0, s1x3 = 0;
            float s2x0 = 0, s2x1 = 0, s2x2 = 0, s2x3 = 0;
            float s1y0 = 0, s1y1 = 0, s1y2 = 0, s1y3 = 0;
            float s2y0 = 0, s2y1 = 0, s2y2 = 0, s2y3 = 0;
#pragma unroll
            for (int rr = 0; rr < 8; ++rr) {
                int r = g2 * 8 + rr;
                int off = r * 128 + (((c4 >> 4) ^ (r & 7)) << 4) + (c4 & 15);
                unsigned wx = *(const unsigned*)&Xc[off];
                unsigned wy = *(const unsigned*)&Yc[off];
                float x0 = __builtin_amdgcn_cvt_f32_fp8(wx, 0);
                float x1 = __builtin_amdgcn_cvt_f32_fp8(wx, 1);
                float x2 = __builtin_amdgcn_cvt_f32_fp8(wx, 2);
                float x3 = __builtin_amdgcn_cvt_f32_fp8(wx, 3);
                float y0 = __builtin_amdgcn_cvt_f32_fp8(wy, 0);
                float y1 = __builtin_amdgcn_cvt_f32_fp8(wy, 1);
                float y2 = __builtin_amdgcn_cvt_f32_fp8(wy, 2);
                float y3 = __builtin_amdgcn_cvt_f32_fp8(wy, 3);
                s1x0 += x0; s1x1 += x1; s1x2 += x2; s1x3 += x3;
                s2x0 = fmaf(x0, x0, s2x0); s2x1 = fmaf(x1, x1, s2x1);
                s2x2 = fmaf(x2, x2, s2x2); s2x3 = fmaf(x3, x3, s2x3);
                s1y0 += y0; s1y1 += y1; s1y2 += y2; s1y3 += y3;
                s2y0 = fmaf(y0, y0, s2y0); s2y1 = fmaf(y1, y1, s2y1);
                s2y2 = fmaf(y2, y2, s2y2); s2y3 = fmaf(y3, y3, s2y3);
            }
            s1x0 += __shfl_xor(s1x0, 32, 64); s1x1 += __shfl_xor(s1x1, 32, 64);
            s1x2 += __shfl_xor(s1x2, 32, 64); s1x3 += __shfl_xor(s1x3, 32, 64);
            s2x0 += __shfl_xor(s2x0, 32, 64); s2x1 += __shfl_xor(s2x1, 32, 64);
            s2x2 += __shfl_xor(s2x2, 32, 64); s2x3 += __shfl_xor(s2x3, 32, 64);
            s1y0 += __shfl_xor(s1y0, 32, 64); s1y1 += __shfl_xor(s1y1, 32, 64);
            s1y2 += __shfl_xor(s1y2, 32, 64); s1y3 += __shfl_xor(s1y3, 32, 64);
            s2y0 += __shfl_xor(s2y0, 32, 64); s2y1 += __shfl_xor(s2y1, 32, 64);
            s2y2 += __shfl_xor(s2y2, 32, 64); s2y3 += __shfl_xor(s2y3, 32, 64);
            if (l < 32) {
                *(float4*)&colpart[w][0][c4] = make_float4(s1x0, s1x1, s1x2, s1x3);
                *(float4*)&colpart[w][1][c4] = make_float4(s2x0, s2x1, s2x2, s2x3);
                *(float4*)&colpart[w][2][c4] = make_float4(s1y0, s1y1, s1y2, s1y3);
                *(float4*)&colpart[w][3][c4] = make_float4(s2y0, s2y1, s2y2, s2y3);
            }
        }
        __syncthreads();   // stats of chunk kc visible

        if (t < 128) {
            float s1x = 0, s2x = 0, s1y = 0, s2y = 0;
#pragma unroll
            for (int ww = 0; ww < 4; ++ww) {
                s1x += colpart[ww][0][t]; s2x += colpart[ww][1][t];
                s1y += colpart[ww][2][t]; s2y += colpart[ww][3][t];
            }
            float sx = s2x - s1x * s1x * (1.f / 64.f);
            float sy = s2y - s1y * s1y * (1.f / 64.f);
            stdacc += fmaxf(0.f, 1.f - sqrtf(sx * (1.f / 63.f) + 1e-4f)) +
                      fmaxf(0.f, 1.f - sqrtf(sy * (1.f / 63.f) + 1e-4f));
            covdacc += sx * sx + sy * sy;
            reprp += s2x + s2y;
        }
        __syncthreads();   // WAR: colpart reads done before next chunk writes
    }

    // ---- epilogue (identical structure to bf16 4-wave version) ----
    float zd = 0.f;
    {
        int rbase = (l >> 4) << 2, col = l & 15;
#pragma unroll
        for (int reg = 0; reg < 4; ++reg)
            zd += (col == rbase + reg) ? Z[reg] : 0.f;
    }
    float rsx[4], rsy[4];
#pragma unroll
    for (int reg = 0; reg < 4; ++reg) {
        rsx[reg] = Gx[0][reg] + Gx[1][reg] + Gx[2][reg] + Gx[3][reg];
        rsy[reg] = Gy[0][reg] + Gy[1][reg] + Gy[2][reg] + Gy[3][reg];
    }
#pragma unroll
    for (int off = 1; off < 16; off <<= 1)
#pragma unroll
        for (int reg = 0; reg < 4; ++reg) {
            rsx[reg] += __shfl_xor(rsx[reg], off, 64);
            rsy[reg] += __shfl_xor(rsy[reg], off, 64);
        }
    if ((l & 15) == 0) {
#pragma unroll
        for (int reg = 0; reg < 4; ++reg) {
            Rsx[(w << 4) + ((l >> 4) << 2) + reg] = rsx[reg];
            Rsy[(w << 4) + ((l >> 4) << 2) + reg] = rsy[reg];
        }
    }
    __syncthreads();
    float myx = Rsx[l], myy = Rsy[l];
#pragma unroll
    for (int off = 1; off < 64; off <<= 1) {
        myx += __shfl_xor(myx, off, 64);
        myy += __shfl_xor(myy, off, 64);
    }
    float tX = myx * (1.f / 4096.f), tY = myy * (1.f / 4096.f);
    float kn = 0.f;
#pragma unroll
    for (int j = 0; j < 4; ++j) {
        float cX = Rsx[(j << 4) + (l & 15)] * (1.f / 64.f);
        float cY = Rsy[(j << 4) + (l & 15)] * (1.f / 64.f);
#pragma unroll
        for (int reg = 0; reg < 4; ++reg) {
            float K1 = Gx[j][reg] - rsx[reg] * (1.f / 64.f) - cX + tX;
            kn = fmaf(K1, K1, kn);
            float K2 = Gy[j][reg] - rsy[reg] * (1.f / 64.f) - cY + tY;
            kn = fmaf(K2, K2, kn);
        }
    }

    float v0 = reprp - 2.f * zd, v1 = stdacc, v2 = covdacc, v3 = kn;
#pragma unroll
    for (int off = 1; off < 64; off <<= 1) {
        v0 += __shfl_xor(v0, off, 64);
        v1 += __shfl_xor(v1, off, 64);
        v2 += __shfl_xor(v2, off, 64);
        v3 += __shfl_xor(v3, off, 64);
    }
    if (l == 0) { redsc[w][0] = v0; redsc[w][1] = v1; redsc[w][2] = v2; redsc[w][3] = v3; }
    __syncthreads();
    if (t == 0) {
        float r0 = 0, r1 = 0, r2 = 0, r3 = 0;
#pragma unroll
        for (int ww = 0; ww < 4; ++ww) {
            r0 += redsc[ww][0]; r1 += redsc[ww][1];
            r2 += redsc[ww][2]; r3 += redsc[ww][3];
        }
        atomicAdd(&acc[0], r0);
        atomicAdd(&acc[1], r1);
        atomicAdd(&acc[2], r3 - r2);
        __threadfence();
        unsigned old = atomicAdd((unsigned*)&acc[6], 1u);
        if (old == 4 * M - 1) {
            float a0 = atomicAdd(&acc[0], 0.f);
            float a1 = atomicAdd(&acc[1], 0.f);
            float a2 = atomicAdd(&acc[2], 0.f);
            float repr = 25.f * a0 / ((float)B * (float)M * (float)C);
            float stdl = 12.5f * a1 / ((float)M * (float)C);
            float cov = a2 / (63.f * 63.f * (float)C * 2.f) / (float)M;
            outp[0] = repr + stdl + cov;
        }
    }
}

// ---------------------------------------------------------------------------
// bf16 VICReg fallback (8-wave K-split, R10 version) — used if ws can't hold
// the fp8 shadow copies.
// ---------------------------------------------------------------------------
__global__ __launch_bounds__(512, 1) void vicreg_mfma_kernel(
    const u16* __restrict__ abf, const u16* __restrict__ bbf,
    const int* __restrict__ sel_idx, const int* __restrict__ nn_idx,
    float* __restrict__ acc, float* __restrict__ outp) {
    const int mloc = blockIdx.x;
    const int p = blockIdx.y;
    const int t = threadIdx.x;
    const int l = t & 63, w = t >> 6;
    const int kh = w >> 2, wl = w & 3;

    __shared__ __align__(16) u16 Xs[4][64 * 128];
    __shared__ __align__(16) u16 Ys[4][64 * 128];
    __shared__ float colpart[2][4][4][128];
    __shared__ float Rsx[64], Rsy[64];
    __shared__ int xi[64], yi[64];
    __shared__ float redsc[4][4];

    if (t < 64) xi[t] = sel_idx[((size_t)p * B + t) * M + mloc];
    else if (t < 128) yi[t - 64] = nn_idx[((size_t)p * B + (t - 64)) * M + mloc];
    __syncthreads();

    const u16* Xg = (p & 1) ? bbf : abf;
    const u16* Yg = (p & 1) ? abf : bbf;
    unsigned xofs[4], yofs[4];
    int ldst[4];
#pragma unroll
    for (int s = 0; s < 4; ++s) {
        int r = wl * 16 + s * 4 + (l >> 4);
        int cs = (l & 15) ^ (r & 15);
        xofs[s] = (unsigned)((r * N + xi[r]) * C + cs * 8);
        yofs[s] = (unsigned)((r * N + yi[r]) * C + cs * 8);
        ldst[s] = (wl * 16 + s * 4) * 128;
    }

#pragma unroll
    for (int cc = 0; cc < 2; ++cc) {
        int kc = 2 * kh + cc;
#pragma unroll
        for (int s = 0; s < 4; ++s) {
            gload_lds16(Xg + xofs[s] + kc * 128, &Xs[kc][ldst[s]]);
            gload_lds16(Yg + yofs[s] + kc * 128, &Ys[kc][ldst[s]]);
        }
    }
    __syncthreads();

    f32x4 Gx[4], Gy[4], Z;
#pragma unroll
    for (int j = 0; j < 4; ++j) { Gx[j] = (f32x4){0,0,0,0}; Gy[j] = (f32x4){0,0,0,0}; }
    Z = (f32x4){0, 0, 0, 0};
    float stdacc = 0.f, covdacc = 0.f, reprp = 0.f;

#pragma unroll
    for (int cc = 0; cc < 2; ++cc) {
        const int kc = 2 * kh + cc;
        const u16* Xc = Xs[kc];
        const u16* Yc = Ys[kc];
#pragma unroll
        for (int ks = 0; ks < 4; ++ks) {
            int cb = ks * 4 + (l >> 4);
            int pe = (cb ^ (l & 15)) << 3;
            short8 ax = *(const short8*)&Xc[((wl << 4) + (l & 15)) * 128 + pe];
            short8 ay = *(const short8*)&Yc[((wl << 4) + (l & 15)) * 128 + pe];
            short8 bx[4], by[4];
#pragma unroll
            for (int j = 0; j < 4; ++j) {
                bx[j] = *(const short8*)&Xc[(j * 16 + (l & 15)) * 128 + pe];
                by[j] = *(const short8*)&Yc[(j * 16 + (l & 15)) * 128 + pe];
            }
#pragma unroll
            for (int j = 0; j < 4; ++j) {
                Gx[j] = __builtin_amdgcn_mfma_f32_16x16x32_bf16(ax, bx[j], Gx[j], 0, 0, 0);
                Gy[j] = __builtin_amdgcn_mfma_f32_16x16x32_bf16(ay, by[j], Gy[j], 0, 0, 0);
            }
            Z = __builtin_amdgcn_mfma_f32_16x16x32_bf16(ax, ay, Z, 0, 0, 0);
        }
        {
            int c4 = (l & 31) << 2;
            int cc8 = c4 >> 3, h = (c4 >> 2) & 1;
            int g2 = (wl << 1) + (l >> 5);
            float s1x0 = 0, s1x1 = 0, s1x2 = 0, s1x3 = 0;
            float s2x0 = 0, s2x1 = 0, s2x2 = 0, s2x3 = 0;
            float s1y0 = 0, s1y1 = 0, s1y2 = 0, s1y3 = 0;
            float s2y0 = 0, s2y1 = 0, s2y2 = 0, s2y3 = 0;
#pragma unroll
            for (int rr = 0; rr < 8; ++rr) {
                int r = g2 * 8 + rr;
                int off = r * 128 + ((cc8 ^ (r & 15)) << 3) + h * 4;
                ushort4 vx = *(const ushort4*)&Xc[off];
                ushort4 vy = *(const ushort4*)&Yc[off];
                float x0 = b2f(vx.x), x1 = b2f(vx.y), x2 = b2f(vx.z), x3 = b2f(vx.w);
                float y0 = b2f(vy.x), y1 = b2f(vy.y), y2 = b2f(vy.z), y3 = b2f(vy.w);
                s1x0 += x0; s1x1 += x1; s1x2 += x2; s1x3 += x3;
                s2x0 = fmaf(x0, x0, s2x0); s2x1 = fmaf(x1, x1, s2x1);
                s2x2 = fmaf(x2, x2, s2x2); s2x3 = fmaf(x3, x3, s2x3);
                s1y0 += y0; s1y1 += y1; s1y2 += y2; s1y3 += y3;
                s2y0 = fmaf(y0, y0, s2y0); s2y1 = fmaf(y1, y1, s2y1);
                s2y2 = fmaf(y2, y2, s2y2); s2y3 = fmaf(y3, y3, s2y3);
            }
            s1x0 += __shfl_xor(s1x0, 32, 64); s1x1 += __shfl_xor(s1x1, 32, 64);
            s1x2 += __shfl_xor(s1x2, 32, 64); s1x3 += __shfl_xor(s1x3, 32, 64);
            s2x0 += __shfl_xor(s2x0, 32, 64); s2x1 += __shfl_xor(s2x1, 32, 64);
            s2x2 += __shfl_xor(s2x2, 32, 64); s2x3 += __shfl_xor(s2x3, 32, 64);
            s1y0 += __shfl_xor(s1y0, 32, 64); s1y1 += __shfl_xor(s1y1, 32, 64);
            s1y2 += __shfl_xor(s1y2, 32, 64); s1y3 += __shfl_xor(s1y3, 32, 64);
            s2y0 += __shfl_xor(s2y0, 32, 64); s2y1 += __shfl_xor(s2y1, 32, 64);
            s2y2 += __shfl_xor(s2y2, 32, 64); s2y3 += __shfl_xor(s2y3, 32, 64);
            if (l < 32) {
                *(float4*)&colpart[kh][wl][0][c4] = make_float4(s1x0, s1x1, s1x2, s1x3);
                *(float4*)&colpart[kh][wl][1][c4] = make_float4(s2x0, s2x1, s2x2, s2x3);
                *(float4*)&colpart[kh][wl][2][c4] = make_float4(s1y0, s1y1, s1y2, s1y3);
                *(float4*)&colpart[kh][wl][3][c4] = make_float4(s2y0, s2y1, s2y2, s2y3);
            }
        }
        __syncthreads();
        if (t < 256) {
            int khp = t >> 7, col = t & 127;
            float s1x = 0, s2x = 0, s1y = 0, s2y = 0;
#pragma unroll
            for (int ww = 0; ww < 4; ++ww) {
                s1x += colpart[khp][ww][0][col]; s2x += colpart[khp][ww][1][col];
                s1y += colpart[khp][ww][2][col]; s2y += colpart[khp][ww][3][col];
            }
            float sx = s2x - s1x * s1x * (1.f / 64.f);
            float sy = s2y - s1y * s1y * (1.f / 64.f);
            stdacc += fmaxf(0.f, 1.f - sqrtf(sx * (1.f / 63.f) + 1e-4f)) +
                      fmaxf(0.f, 1.f - sqrtf(sy * (1.f / 63.f) + 1e-4f));
            covdacc += sx * sx + sy * sy;
            reprp += s2x + s2y;
        }
        __syncthreads();
    }

    {
        float* ex = (float*)&Xs[0][0];
        int base = ((wl << 6) + l) * 36;
        if (kh == 1) {
#pragma unroll
            for (int j = 0; j < 4; ++j)
#pragma unroll
                for (int reg = 0; reg < 4; ++reg) {
                    ex[base + j * 4 + reg] = Gx[j][reg];
                    ex[base + 16 + j * 4 + reg] = Gy[j][reg];
                }
#pragma unroll
            for (int reg = 0; reg < 4; ++reg) ex[base + 32 + reg] = Z[reg];
        }
        __syncthreads();
        if (kh == 0) {
#pragma unroll
            for (int j = 0; j < 4; ++j)
#pragma unroll
                for (int reg = 0; reg < 4; ++reg) {
                    Gx[j][reg] += ex[base + j * 4 + reg];
                    Gy[j][reg] += ex[base + 16 + j * 4 + reg];
                }
#pragma unroll
            for (int reg = 0; reg < 4; ++reg) Z[reg] += ex[base + 32 + reg];
        }
    }

    float zd = 0.f;
    float rsx[4] = {0, 0, 0, 0}, rsy[4] = {0, 0, 0, 0};
    if (kh == 0) {
        int rbase = (l >> 4) << 2, col = l & 15;
#pragma unroll
        for (int reg = 0; reg < 4; ++reg)
            zd += (col == rbase + reg) ? Z[reg] : 0.f;
#pragma unroll
        for (int reg = 0; reg < 4; ++reg) {
            rsx[reg] = Gx[0][reg] + Gx[1][reg] + Gx[2][reg] + Gx[3][reg];
            rsy[reg] = Gy[0][reg] + Gy[1][reg] + Gy[2][reg] + Gy[3][reg];
        }
#pragma unroll
        for (int off = 1; off < 16; off <<= 1)
#pragma unroll
            for (int reg = 0; reg < 4; ++reg) {
                rsx[reg] += __shfl_xor(rsx[reg], off, 64);
                rsy[reg] += __shfl_xor(rsy[reg], off, 64);
            }
        if ((l & 15) == 0) {
#pragma unroll
            for (int reg = 0; reg < 4; ++reg) {
                Rsx[(wl << 4) + ((l >> 4) << 2) + reg] = rsx[reg];
                Rsy[(wl << 4) + ((l >> 4) << 2) + reg] = rsy[reg];
            }
        }
    }
    __syncthreads();
    if (kh == 0) {
        float myx = Rsx[l], myy = Rsy[l];
#pragma unroll
        for (int off = 1; off < 64; off <<= 1) {
            myx += __shfl_xor(myx, off, 64);
            myy += __shfl_xor(myy, off, 64);
        }
        float tX = myx * (1.f / 4096.f), tY = myy * (1.f / 4096.f);
        float kn = 0.f;
#pragma unroll
        for (int j = 0; j < 4; ++j) {
            float cX = Rsx[(j << 4) + (l & 15)] * (1.f / 64.f);
            float cY = Rsy[(j << 4) + (l & 15)] * (1.f / 64.f);
#pragma unroll
            for (int reg = 0; reg < 4; ++reg) {
                float K1 = Gx[j][reg] - rsx[reg] * (1.f / 64.f) - cX + tX;
                kn = fmaf(K1, K1, kn);
                float K2 = Gy[j][reg] - rsy[reg] * (1.f / 64.f) - cY + tY;
                kn = fmaf(K2, K2, kn);
            }
        }
        float v0 = reprp - 2.f * zd, v1 = stdacc, v2 = covdacc, v3 = kn;
#pragma unroll
        for (int off = 1; off < 64; off <<= 1) {
            v0 += __shfl_xor(v0, off, 64);
            v1 += __shfl_xor(v1, off, 64);
            v2 += __shfl_xor(v2, off, 64);
            v3 += __shfl_xor(v3, off, 64);
        }
        if (l == 0) { redsc[wl][0] = v0; redsc[wl][1] = v1;
                      redsc[wl][2] = v2; redsc[wl][3] = v3; }
    }
    __syncthreads();
    if (t == 0) {
        float r0 = 0, r1 = 0, r2 = 0, r3 = 0;
#pragma unroll
        for (int ww = 0; ww < 4; ++ww) {
            r0 += redsc[ww][0]; r1 += redsc[ww][1];
            r2 += redsc[ww][2]; r3 += redsc[ww][3];
        }
        atomicAdd(&acc[0], r0);
        atomicAdd(&acc[1], r1);
        atomicAdd(&acc[2], r3 - r2);
        __threadfence();
        unsigned old = atomicAdd((unsigned*)&acc[6], 1u);
        if (old == 4 * M - 1) {
            float a0 = atomicAdd(&acc[0], 0.f);
            float a1 = atomicAdd(&acc[1], 0.f);
            float a2 = atomicAdd(&acc[2], 0.f);
            float repr = 25.f * a0 / ((float)B * (float)M * (float)C);
            float stdl = 12.5f * a1 / ((float)M * (float)C);
            float cov = a2 / (63.f * 63.f * (float)C * 2.f) / (float)M;
            outp[0] = repr + stdl + cov;
        }
    }
}

// ---------------------------------------------------------------------------
// FALLBACK fp32 path kernels (only if ws can't hold bf16 copies)
// ---------------------------------------------------------------------------
__global__ __launch_bounds__(256) void init_kernel(u64* rowkey, float* acc) {
    int i = blockIdx.x * 256 + threadIdx.x;
    if (i < 4 * B * N) rowkey[i] = ~0ull;
    if (i < 8) acc[i] = 0.f;
}

__global__ __launch_bounds__(256) void norms_kernel(const float* __restrict__ m1,
                                                    const float* __restrict__ m2,
                                                    float* __restrict__ nrm) {
    int w = blockIdx.x * 4 + (threadIdx.x >> 6);
    int lane = threadIdx.x & 63;
    if (w >= 2 * B * N) return;
    const float* src = (w < B * N) ? m1 : m2;
    int row = (w < B * N) ? w : w - B * N;
    const float4* p = (const float4*)(src + (size_t)row * C);
    float s = 0.f;
#pragma unroll
    for (int i = 0; i < 2; ++i) {
        float4 v = p[lane + i * 64];
        s += v.x * v.x + v.y * v.y + v.z * v.z + v.w * v.w;
    }
#pragma unroll
    for (int off = 32; off > 0; off >>= 1) s += __shfl_down(s, off, 64);
    if (lane == 0) nrm[w] = s;
}

__global__ __launch_bounds__(256) void feat_dist_kernel(
    const float* __restrict__ m1, const float* __restrict__ m2,
    const float* __restrict__ nrm, u64* __restrict__ rowkey) {
    const int b = blockIdx.z;
    const int tn = blockIdx.x, tm = blockIdx.y;
    __shared__ float As[64][68];
    __shared__ float Bt[64][68];
    __shared__ u64 red[64][16];
    const int t = threadIdx.x;
    const int ty = t >> 4, tx = t & 15;
    float acc[4][4] = {};
    const float* A = m1 + (size_t)b * N * C;
    const float* Bm = m2 + (size_t)b * N * C;

    for (int k0 = 0; k0 < C; k0 += 64) {
#pragma unroll
        for (int it = 0; it < 4; ++it) {
            int idx = t + it * 256;
            int r = idx >> 4, cc = (idx & 15) << 2;
            int n = tn * 64 + r;
            float4 v = make_float4(0.f, 0.f, 0.f, 0.f);
            if (n < N) v = *(const float4*)(A + (size_t)n * C + k0 + cc);
            *(float4*)&As[r][cc] = v;
            int mm = tm * 64 + r;
            float4 w = make_float4(0.f, 0.f, 0.f, 0.f);
            if (mm < N) w = *(const float4*)(Bm + (size_t)mm * C + k0 + cc);
            Bt[cc + 0][r] = w.x; Bt[cc + 1][r] = w.y;
            Bt[cc + 2][r] = w.z; Bt[cc + 3][r] = w.w;
        }
        __syncthreads();
#pragma unroll 4
        for (int kq = 0; kq < 64; kq += 4) {
            float aa[4][4], bb[4][4];
#pragma unroll
            for (int i = 0; i < 4; ++i) {
                float4 v = *(const float4*)&As[ty * 4 + i][kq];
                aa[i][0] = v.x; aa[i][1] = v.y; aa[i][2] = v.z; aa[i][3] = v.w;
            }
#pragma unroll
            for (int qq = 0; qq < 4; ++qq) {
                float4 v = *(const float4*)&Bt[kq + qq][tx * 4];
                bb[qq][0] = v.x; bb[qq][1] = v.y; bb[qq][2] = v.z; bb[qq][3] = v.w;
            }
#pragma unroll
            for (int qq = 0; qq < 4; ++qq)
#pragma unroll
                for (int i = 0; i < 4; ++i)
#pragma unroll
                    for (int j = 0; j < 4; ++j)
                        acc[i][j] = fmaf(aa[i][qq], bb[qq][j], acc[i][j]);
        }
        __syncthreads();
    }

    u64 rk[4] = {~0ull, ~0ull, ~0ull, ~0ull};
    u64 ck[4] = {~0ull, ~0ull, ~0ull, ~0ull};
    const float* nr1 = nrm;
    const float* nr2 = nrm + B * N;
#pragma unroll
    for (int i = 0; i < 4; ++i) {
        int n = tn * 64 + ty * 4 + i;
        if (n >= N) continue;
        float a2 = nr1[b * N + n];
#pragma unroll
        for (int j = 0; j < 4; ++j) {
            int mm = tm * 64 + tx * 4 + j;
            if (mm >= N) continue;
            float b2 = nr2[b * N + mm];
            float d2 = a2 + b2 - 2.f * acc[i][j];
            unsigned vb = __float_as_uint(fmaxf(d2, 0.f));
            u64 kv = ((u64)vb << 32);
            rk[i] = umin64(rk[i], kv | (unsigned)mm);
            ck[j] = umin64(ck[j], kv | (unsigned)n);
        }
    }
#pragma unroll
    for (int i = 0; i < 4; ++i) red[ty * 4 + i][tx] = rk[i];
    __syncthreads();
    if (t < 64) {
        u64 best = red[t][0];
#pragma unroll
        for (int x = 1; x < 16; ++x) best = umin64(best, red[t][x]);
        int n = tn * 64 + t;
        if (n < N && best != ~0ull)
            atomicMin(&rowkey[(size_t)b * N + n], best);
    }
    __syncthreads();
#pragma unroll
    for (int j = 0; j < 4; ++j) red[tx * 4 + j][ty] = ck[j];
    __syncthreads();
    if (t < 64) {
        u64 best = red[t][0];
#pragma unroll
        for (int x = 1; x < 16; ++x) best = umin64(best, red[t][x]);
        int mm = tm * 64 + t;
        if (mm < N && best != ~0ull)
            atomicMin(&rowkey[(size_t)B * N + (size_t)b * N + mm], best);
    }
}

__device__ __forceinline__ float blockReduce(float v, float* redb, int t) {
    __syncthreads();
    redb[t] = v;
    __syncthreads();
    for (int s = 128; s > 0; s >>= 1) {
        if (t < s) redb[t] += redb[t + s];
        __syncthreads();
    }
    return redb[0];
}

__global__ __launch_bounds__(256) void vicreg_kernel(
    const float* __restrict__ m1, const float* __restrict__ m2,
    const int* __restrict__ sel_idx, const int* __restrict__ nn_idx,
    float* __restrict__ acc) {
    const int mloc = blockIdx.x;
    const int p = blockIdx.y;
    const int t = threadIdx.x;
    const float* X = (p & 1) ? m2 : m1;
    const float* Y = (p & 1) ? m1 : m2;
    __shared__ float Xs[64][65];
    __shared__ float Ys[64][65];
    __shared__ int xi[64], yi[64];
    __shared__ float pst[192][5];
    __shared__ float Rs[64];
    __shared__ float Tsh;
    __shared__ float redb[256];

    if (t < 64) {
        xi[t] = sel_idx[((size_t)p * B + t) * M + mloc];
        yi[t] = nn_idx[((size_t)p * B + t) * M + mloc];
    }
    __syncthreads();

    float Gx[4][4] = {}, Gy[4][4] = {};
    float stdx = 0, stdy = 0, covdx = 0, covdy = 0, repr = 0;
    const int i0 = (t >> 4) << 2, j0 = (t & 15) << 2;

    for (int c0 = 0; c0 < C; c0 += 64) {
#pragma unroll
        for (int it = 0; it < 4; ++it) {
            int fidx = t + it * 256;
            int r = fidx >> 4, cc = (fidx & 15) << 2;
            float4 v = *(const float4*)(X + ((size_t)r * N + xi[r]) * C + c0 + cc);
            Xs[r][cc] = v.x; Xs[r][cc + 1] = v.y; Xs[r][cc + 2] = v.z; Xs[r][cc + 3] = v.w;
            float4 w = *(const float4*)(Y + ((size_t)r * N + yi[r]) * C + c0 + cc);
            Ys[r][cc] = w.x; Ys[r][cc + 1] = w.y; Ys[r][cc + 2] = w.z; Ys[r][cc + 3] = w.w;
        }
        __syncthreads();
#pragma unroll 4
        for (int k = 0; k < 64; ++k) {
            float ax[4], bx[4], ay[4], by[4];
#pragma unroll
            for (int i = 0; i < 4; ++i) { ax[i] = Xs[i0 + i][k]; ay[i] = Ys[i0 + i][k]; }
#pragma unroll
            for (int j = 0; j < 4; ++j) { bx[j] = Xs[j0 + j][k]; by[j] = Ys[j0 + j][k]; }
#pragma unroll
            for (int i = 0; i < 4; ++i)
#pragma unroll
                for (int j = 0; j < 4; ++j) {
                    Gx[i][j] = fmaf(ax[i], bx[j], Gx[i][j]);
                    Gy[i][j] = fmaf(ay[i], by[j], Gy[i][j]);
                }
        }
        {
            float s1x = 0, s2x = 0, s1y = 0, s2y = 0, sxy = 0;
            int col = t & 63, g = t >> 6;
            for (int r = g * 16; r < g * 16 + 16; ++r) {
                float xv = Xs[r][col], yv = Ys[r][col];
                s1x += xv; s2x += xv * xv;
                s1y += yv; s2y += yv * yv;
                sxy += xv * yv;
            }
            if (g) {
                float* qq = pst[(g - 1) * 64 + col];
                qq[0] = s1x; qq[1] = s2x; qq[2] = s1y; qq[3] = s2y; qq[4] = sxy;
            }
            __syncthreads();
            if (g == 0) {
#pragma unroll
                for (int gg = 0; gg < 3; ++gg) {
                    float* qq = pst[gg * 64 + col];
                    s1x += qq[0]; s2x += qq[1]; s1y += qq[2]; s2y += qq[3]; sxy += qq[4];
                }
                float xb = s1x * (1.f / 64.f);
                float sx = s2x - 64.f * xb * xb;
                float yb = s1y * (1.f / 64.f);
                float sy = s2y - 64.f * yb * yb;
                stdx += fmaxf(0.f, 1.f - sqrtf(sx * (1.f / 63.f) + 1e-4f));
                stdy += fmaxf(0.f, 1.f - sqrtf(sy * (1.f / 63.f) + 1e-4f));
                covdx += sx * sx;
                covdy += sy * sy;
                repr += s2x + s2y - 2.f * sxy;
            }
            __syncthreads();
        }
    }

    float knx = 0.f, kny = 0.f;
    float (*Gs)[65] = (float(*)[65]) & Xs[0][0];
    __syncthreads();
#pragma unroll
    for (int i = 0; i < 4; ++i)
#pragma unroll
        for (int j = 0; j < 4; ++j) Gs[i0 + i][j0 + j] = Gx[i][j];
    __syncthreads();
    if (t < 64) {
        float r = 0;
        for (int j = 0; j < 64; ++j) r += Gs[t][j];
        Rs[t] = r;
    }
    __syncthreads();
    if (t < 64) {
        float r = Rs[t];
#pragma unroll
        for (int off = 32; off > 0; off >>= 1) r += __shfl_down(r, off, 64);
        if (t == 0) Tsh = r;
    }
    __syncthreads();
    {
        float T = Tsh * (1.f / 4096.f);
#pragma unroll
        for (int i = 0; i < 4; ++i)
#pragma unroll
            for (int j = 0; j < 4; ++j) {
                float Kij = Gx[i][j] - (Rs[i0 + i] + Rs[j0 + j]) * (1.f / 64.f) + T;
                knx = fmaf(Kij, Kij, knx);
            }
    }
    __syncthreads();
#pragma unroll
    for (int i = 0; i < 4; ++i)
#pragma unroll
        for (int j = 0; j < 4; ++j) Gs[i0 + i][j0 + j] = Gy[i][j];
    __syncthreads();
    if (t < 64) {
        float r = 0;
        for (int j = 0; j < 64; ++j) r += Gs[t][j];
        Rs[t] = r;
    }
    __syncthreads();
    if (t < 64) {
        float r = Rs[t];
#pragma unroll
        for (int off = 32; off > 0; off >>= 1) r += __shfl_down(r, off, 64);
        if (t == 0) Tsh = r;
    }
    __syncthreads();
    {
        float T = Tsh * (1.f / 4096.f);
#pragma unroll
        for (int i = 0; i < 4; ++i)
#pragma unroll
            for (int j = 0; j < 4; ++j) {
                float Kij = Gy[i][j] - (Rs[i0 + i] + Rs[j0 + j]) * (1.f / 64.f) + T;
                kny = fmaf(Kij, Kij, kny);
            }
    }

    float v_repr = blockReduce(repr, redb, t);
    float v_std = blockReduce(stdx + stdy, redb, t);
    float v_covd = blockReduce(covdx + covdy, redb, t);
    float v_kn = blockReduce(knx + kny, redb, t);
    if (t == 0) {
        atomicAdd(&acc[0], v_repr);
        atomicAdd(&acc[1], v_std);
        atomicAdd(&acc[2], v_kn - v_covd);
    }
}

// ---------------------------------------------------------------------------
__global__ void finalize_kernel(const float* __restrict__ acc, float* __restrict__ out) {
    if (threadIdx.x == 0 && blockIdx.x == 0) {
        float repr = 25.f * acc[0] / ((float)B * (float)M * (float)C);
        float stdl = 12.5f * acc[1] / ((float)M * (float)C);
        float cov = acc[2] / (63.f * 63.f * (float)C * 2.f) / (float)M;
        out[0] = repr + stdl + cov;
    }
}

// ---------------------------------------------------------------------------
extern "C" void kernel_launch(void* const* d_in, const int* in_sizes, int n_in,
                              void* d_out, int out_size, void* d_ws, size_t ws_size,
                              hipStream_t stream) {
    const float* m1 = (const float*)d_in[0];
    const float* m2 = (const float*)d_in[1];
    const float* l1 = (const float*)d_in[2];
    const float* l2 = (const float*)d_in[3];
    float* out = (float*)d_out;
    char* ws = (char*)d_ws;

    u64* rowkey = (u64*)ws;                                   // [4][B][N]
    size_t off = (size_t)4 * B * N * sizeof(u64);
    float* nrm = (float*)(ws + off); off += (size_t)2 * B * N * sizeof(float);
    int* sel_idx = (int*)(ws + off); off += (size_t)4 * B * M * sizeof(int);
    int* nn_idx = (int*)(ws + off);  off += (size_t)4 * B * M * sizeof(int);
    float* acc = (float*)(ws + off); off += 256;
    off = (off + 255) & ~(size_t)255;
    u16* abf = (u16*)(ws + off);
    u16* bbf = abf + (size_t)B * N * C;
    size_t need = off + (size_t)2 * B * N * C * sizeof(u16);
    u8* a8 = (u8*)(ws + need);
    u8* b8 = a8 + (size_t)B * N * C;
    size_t need8 = need + (size_t)2 * B * N * C;
    bool use_mfma = ws_size >= need;          // ws_size fixed -> deterministic
    bool use_fp8 = ws_size >= need8;

    // ws is NOT re-poisoned between replays: every launch re-inits all state
    // it reads. MFMA path: convnorm clears rowkey dirs 0,1; loc_dist
    // plain-stores dirs 2,3; select zeroes acc[0..7] (incl. completion
    // counter acc[6]); vicreg finalizes out[0].
    if (use_mfma) {
        convnorm_kernel<<<dim3(2 * B * N / 4), dim3(256), 0, stream>>>(
            m1, m2, abf, bbf, a8, b8, nrm, rowkey, (int)use_fp8);
        feat_mfma_kernel<<<dim3(64 * 49), dim3(256), 0, stream>>>(abf, bbf, nrm, rowkey);
        loc_dist_kernel<<<dim3((N + 255) / 256, B, 2), dim3(256), 0, stream>>>(l1, l2, rowkey);
        select_kernel<<<dim3(B, 4), dim3(256), 0, stream>>>(rowkey, sel_idx, nn_idx, acc);
        if (use_fp8) {
            vicreg_fp8_kernel<<<dim3(M, 4), dim3(256), 0, stream>>>(
                a8, b8, sel_idx, nn_idx, acc, out);
        } else {
            vicreg_mfma_kernel<<<dim3(M, 4), dim3(512), 0, stream>>>(
                abf, bbf, sel_idx, nn_idx, acc, out);
        }
    } else {
        init_kernel<<<dim3((4 * B * N + 255) / 256), dim3(256), 0, stream>>>(rowkey, acc);
        norms_kernel<<<dim3(2 * B * N / 4), dim3(256), 0, stream>>>(m1, m2, nrm);
        feat_dist_kernel<<<dim3(13, 13, B), dim3(256), 0, stream>>>(m1, m2, nrm, rowkey);
        loc_dist_kernel<<<dim3((N + 255) / 256, B, 2), dim3(256), 0, stream>>>(l1, l2, rowkey);
        select_kernel<<<dim3(B, 4), dim3(256), 0, stream>>>(rowkey, sel_idx, nn_idx, acc);
        vicreg_kernel<<<dim3(M, 4), dim3(256), 0, stream>>>(m1, m2, sel_idx, nn_idx, acc);
        finalize_kernel<<<dim3(1), dim3(64), 0, stream>>>(acc, out);
    }
}

// Round 12
// 243.235 us; speedup vs baseline: 1.1353x; 1.1353x over previous
//
#include <hip/hip_runtime.h>
#include <stdint.h>

#define B 64
#define N 784
#define C 512
#define M 256

typedef unsigned long long u64;
typedef unsigned short u16;
typedef unsigned char u8;
typedef long i64;
typedef __attribute__((ext_vector_type(4))) float f32x4;

static __device__ __forceinline__ u64 umin64(u64 a, u64 b) { return a < b ? a : b; }

static __device__ __forceinline__ void gload_lds16b(const u8* g, u8* l) {
    __builtin_amdgcn_global_load_lds((const __attribute__((address_space(1))) void*)g,
                                     (__attribute__((address_space(3))) void*)l, 16, 0, 0);
}

// ---------------------------------------------------------------------------
// fused rowkey init (dirs 0,1) + fp32 -> fp8 e4m3 convert + row |q|^2 norms
// (norms computed from DEQUANTIZED values so feat's d2 is the exact squared
// distance in quantized feature space). One wave per row (512 floats).
// ---------------------------------------------------------------------------
__global__ __launch_bounds__(256) void convnorm_kernel(
    const float* __restrict__ m1, const float* __restrict__ m2,
    u8* __restrict__ a8, u8* __restrict__ b8,
    float* __restrict__ nrm, u64* __restrict__ rowkey) {
    int gid = blockIdx.x * 256 + threadIdx.x;
    if (gid < 2 * B * N) rowkey[gid] = ~0ull;      // dirs 0,1 keys
    int w = blockIdx.x * 4 + (threadIdx.x >> 6);
    int lane = threadIdx.x & 63;
    if (w >= 2 * B * N) return;
    const float* src = (w < B * N) ? m1 : m2;
    u8* dst8 = (w < B * N) ? a8 : b8;
    int row = (w < B * N) ? w : w - B * N;
    const float4* p = (const float4*)(src + (size_t)row * C);
    unsigned* q8 = (unsigned*)(dst8 + (size_t)row * C);
    float s = 0.f;
#pragma unroll
    for (int i = 0; i < 2; ++i) {
        int idx = lane + i * 64;
        float4 v = p[idx];
        int pk = __builtin_amdgcn_cvt_pk_fp8_f32(v.x, v.y, 0, false);
        pk = __builtin_amdgcn_cvt_pk_fp8_f32(v.z, v.w, pk, true);
        q8[idx] = (unsigned)pk;
        float d0 = __builtin_amdgcn_cvt_f32_fp8((unsigned)pk, 0);
        float d1 = __builtin_amdgcn_cvt_f32_fp8((unsigned)pk, 1);
        float d2 = __builtin_amdgcn_cvt_f32_fp8((unsigned)pk, 2);
        float d3 = __builtin_amdgcn_cvt_f32_fp8((unsigned)pk, 3);
        s += d0 * d0 + d1 * d1 + d2 * d2 + d3 * d3;
    }
#pragma unroll
    for (int off = 32; off > 0; off >>= 1) s += __shfl_down(s, off, 64);
    if (lane == 0) nrm[w] = s;
}

// ---------------------------------------------------------------------------
// fp8 MFMA feature-distance: 128x128 tile, BK=128 (1B/elem: same 16KB/operand
// LDS as bf16-BK64 but HALF the K-steps -> half the barrier drains, which
// were the pinned ~20%-MfmaUtil limiter). Counted-vmcnt dbuf, hoisted
// ds_read addresses, 16B-granule XOR swizzle on src+read (rule 21).
// d2 = |qa|^2+|qb|^2-2 qa.qb is the exact squared distance of the quantized
// vectors (norms from dequantized fp8). A/B use identical lane addressing so
// any within-k mapping permutation cancels in the dot products.
// ---------------------------------------------------------------------------
__global__ __launch_bounds__(256, 2) void feat_mfma_kernel(
    const u8* __restrict__ a8, const u8* __restrict__ b8,
    const float* __restrict__ nrm, u64* __restrict__ rowkey) {
    // decode: id = ((b>>3)*49 + tile)*8 + (b&7)  (batch->XCD affinity)
    int id = blockIdx.x;
    int xcd = id & 7;
    int q = id >> 3;
    int hi = q / 49, t49 = q - hi * 49;
    int b = hi * 8 + xcd;
    int tn = t49 / 7, tm = t49 - tn * 7;

    const int t = threadIdx.x;
    const int lane = t & 63, wv = t >> 6;
    const int wr = wv >> 1, wc = wv & 1;

    // union: 2 staging bufs (A 16KB + B 16KB each) / epilogue red[128][33] u64
    __shared__ __align__(16) u8 RAW[65536];
    __shared__ float sNa[128], sNb[128];

    const int row0 = tn * 128, col0 = tm * 128;
    if (t < 128) {
        int n = row0 + t;
        sNa[t] = (n < N) ? nrm[b * N + n] : __builtin_inff();
    } else {
        int m = col0 + (t - 128);
        sNb[t - 128] = (m < N) ? nrm[B * N + b * N + m] : __builtin_inff();
    }

    // staging: instr s covers 16B granule-chunks c=(wv*4+s)*64+lane of the
    // 128x128B tile; LDS linear, source granule XOR-pre-swizzled g^(row&7).
    size_t aofs[4], bofs[4];
    int ldso[4];
#pragma unroll
    for (int s = 0; s < 4; ++s) {
        int c = (wv * 4 + s) * 64 + lane;
        int rl = c >> 3;                       // tile-local row 0..127
        int grp = (c & 7) ^ (rl & 7);          // swizzled 16B granule
        int ga = row0 + rl; if (ga > N - 1) ga = N - 1;
        int gb = col0 + rl; if (gb > N - 1) gb = N - 1;
        aofs[s] = ((size_t)b * N + ga) * C + grp * 16;
        bofs[s] = ((size_t)b * N + gb) * C + grp * 16;
        ldso[s] = (wv * 4 + s) * 1024;
    }

    // hoisted frag-read bases: lane l reads row (blk + f*16 + l15), 8B at
    // k-granule g = ks*2 + h (h=(l>>4)>>1), half wi = ((l>>4)&1)*8.
    const int l15 = lane & 15;
    const int hh = (lane >> 4) >> 1;
    const int wi = ((lane >> 4) & 1) << 3;
    const int sA_base = (wr * 64 + l15) * 128 + wi;
    const int sB_base = (wc * 64 + l15) * 128 + wi;
    int gofs[4];
#pragma unroll
    for (int ks = 0; ks < 4; ++ks)
        gofs[ks] = (((ks << 1) | hh) ^ (l15 & 7)) << 4;

    f32x4 acc[4][4];
#pragma unroll
    for (int i = 0; i < 4; ++i)
#pragma unroll
        for (int j = 0; j < 4; ++j) acc[i][j] = (f32x4){0.f, 0.f, 0.f, 0.f};

    // prologue: stage K-step 0 into buf 0 (8 loads/wave, stay in flight)
    {
        u8* A0 = RAW;
        u8* B0 = RAW + 16384;
#pragma unroll
        for (int s = 0; s < 4; ++s) {
            gload_lds16b(a8 + aofs[s], &A0[ldso[s]]);
            gload_lds16b(b8 + bofs[s], &B0[ldso[s]]);
        }
    }

    for (int kt = 0; kt < 4; ++kt) {
        const int cur = kt & 1;
        if (kt < 3) {
            int ke = (kt + 1) * 128;
            u8* An = RAW + (cur ^ 1) * 32768;
            u8* Bn = An + 16384;
#pragma unroll
            for (int s = 0; s < 4; ++s) {
                gload_lds16b(a8 + aofs[s] + ke, &An[ldso[s]]);
                gload_lds16b(b8 + bofs[s] + ke, &Bn[ldso[s]]);
            }
            // 16 outstanding; wait until only the 8 newest (step kt+1) remain
            asm volatile("s_waitcnt vmcnt(8)" ::: "memory");
        } else {
            asm volatile("s_waitcnt vmcnt(0)" ::: "memory");
        }
        __builtin_amdgcn_s_barrier();   // step kt landed for ALL waves

        const u8* Als = RAW + cur * 32768;
        const u8* Bls = Als + 16384;
        const u8* pA = Als + sA_base;
        const u8* pB = Bls + sB_base;
#pragma unroll
        for (int ks = 0; ks < 4; ++ks) {
            i64 afr[4], bfr[4];
#pragma unroll
            for (int f = 0; f < 4; ++f) {
                afr[f] = *(const i64*)(pA + gofs[ks] + f * 2048);
                bfr[f] = *(const i64*)(pB + gofs[ks] + f * 2048);
            }
#pragma unroll
            for (int fi = 0; fi < 4; ++fi)
#pragma unroll
                for (int fj = 0; fj < 4; ++fj)
                    acc[fi][fj] = __builtin_amdgcn_mfma_f32_16x16x32_fp8_fp8(
                        afr[fi], bfr[fj], acc[fi][fj], 0, 0, 0);
        }
        asm volatile("s_waitcnt lgkmcnt(0)" ::: "memory");  // my reads done
        __builtin_amdgcn_s_barrier();   // all waves' reads done before overwrite
    }

    // ---- merged epilogue (C/D layout: col=lane&15, row=(lane>>4)*4+reg) ----
    const int g4 = (lane >> 4) << 2;
    float na4[4][4], nb4[4];
#pragma unroll
    for (int fi = 0; fi < 4; ++fi) {
        float4 v = *(const float4*)&sNa[wr * 64 + fi * 16 + g4];
        na4[fi][0] = v.x; na4[fi][1] = v.y; na4[fi][2] = v.z; na4[fi][3] = v.w;
    }
#pragma unroll
    for (int fj = 0; fj < 4; ++fj) nb4[fj] = sNb[wc * 64 + fj * 16 + l15];

    u64(*red)[33] = (u64(*)[33])RAW;   // aliases staging (reads drained above)
    u64 ck[4] = {~0ull, ~0ull, ~0ull, ~0ull};
#pragma unroll
    for (int fi = 0; fi < 4; ++fi) {
        int rl = wr * 64 + fi * 16 + g4;
        u64 rk[4] = {~0ull, ~0ull, ~0ull, ~0ull};
#pragma unroll
        for (int fj = 0; fj < 4; ++fj) {
            unsigned colidx = (unsigned)(col0 + wc * 64 + fj * 16 + l15);
#pragma unroll
            for (int reg = 0; reg < 4; ++reg) {
                float d2 = fmaxf(na4[fi][reg] + nb4[fj] - 2.f * acc[fi][fj][reg], 0.f);
                u64 hv = ((u64)__float_as_uint(d2) << 32);
                rk[reg] = umin64(rk[reg], hv | colidx);
                ck[fj] = umin64(ck[fj], hv | (unsigned)(row0 + rl + reg));
            }
        }
#pragma unroll
        for (int reg = 0; reg < 4; ++reg)
            red[rl + reg][(wc << 4) | l15] = rk[reg];
    }
    // dir1: reduce over row-groups within wave, then across waves via atomic
#pragma unroll
    for (int fj = 0; fj < 4; ++fj) {
        u64 best = ck[fj];
        best = umin64(best, __shfl_xor(best, 16, 64));
        best = umin64(best, __shfl_xor(best, 32, 64));
        if (lane < 16) {
            int m = col0 + wc * 64 + fj * 16 + lane;
            if (m < N) atomicMin(&rowkey[(size_t)B * N + (size_t)b * N + m], best);
        }
    }
    __syncthreads();
    // dir0: one thread per row scans 32 candidates
    if (t < 128) {
        u64 best = red[t][0];
#pragma unroll
        for (int x = 1; x < 32; ++x) best = umin64(best, red[t][x]);
        int n = row0 + t;
        if (n < N) atomicMin(&rowkey[(size_t)b * N + n], best);
    }
}

// ---------------------------------------------------------------------------
// Location-space distances (C=2): dirs 2 and 3.
// ---------------------------------------------------------------------------
__global__ __launch_bounds__(256) void loc_dist_kernel(
    const float* __restrict__ l1, const float* __restrict__ l2,
    u64* __restrict__ rowkey) {
    const int dir = blockIdx.z;
    const int b = blockIdx.y;
    const int t = threadIdx.x;
    const int n = blockIdx.x * 256 + t;
    __shared__ __align__(16) float4 s4[N];
    const float* Ap = dir ? l2 : l1;
    const float* Bp = dir ? l1 : l2;
    for (int i = t; i < N; i += 256) {
        float2 qv = ((const float2*)Bp)[b * N + i];
        s4[i] = make_float4(qv.x, qv.y, qv.x * qv.x + qv.y * qv.y, 0.f);
    }
    __syncthreads();
    if (n >= N) return;
    float2 a = ((const float2*)Ap)[b * N + n];
    float a2 = a.x * a.x + a.y * a.y;
    float nax = -2.f * a.x, nay = -2.f * a.y;
    u64 best = ~0ull;
#pragma unroll 4
    for (int mm = 0; mm < N; ++mm) {
        float4 v = s4[mm];
        float d2 = fmaxf(fmaf(nax, v.x, fmaf(nay, v.y, a2 + v.z)), 0.f);
        u64 kv = ((u64)__float_as_uint(d2) << 32) | (unsigned)mm;
        best = kv < best ? kv : best;
    }
    rowkey[(size_t)(2 + dir) * B * N + (size_t)b * N + n] = best;
}

// ---------------------------------------------------------------------------
// Per (dir, b): 256 rows with smallest NN-dist, stable, original order.
// Block (0,0) zero-inits loss accumulators + completion counter acc[6].
// ---------------------------------------------------------------------------
__global__ __launch_bounds__(256) void select_kernel(
    const u64* __restrict__ rowkey, int* __restrict__ sel_idx,
    int* __restrict__ nn_idx, float* __restrict__ acc) {
    const int b = blockIdx.x;
    const int dir = blockIdx.y;
    const int t = threadIdx.x;
    if (b == 0 && dir == 0 && t < 8) acc[t] = 0.f;
    __shared__ u64 sk[1024];
    const u64* rk = rowkey + (size_t)dir * B * N + (size_t)b * N;
    for (int i = t; i < 1024; i += 256)
        sk[i] = (i < N) ? ((rk[i] & 0xFFFFFFFF00000000ull) | (unsigned)i) : ~0ull;
    __syncthreads();
    for (unsigned k = 2; k <= 1024; k <<= 1) {
        for (unsigned j = k >> 1; j > 0; j >>= 1) {
            for (unsigned i = t; i < 1024; i += 256) {
                unsigned ixj = i ^ j;
                if (ixj > i) {
                    u64 x = sk[i], y = sk[ixj];
                    bool up = ((i & k) == 0);
                    if ((x > y) == up) { sk[i] = y; sk[ixj] = x; }
                }
            }
            __syncthreads();
        }
    }
    unsigned myidx = (unsigned)(sk[t] & 0xFFFFFFFFull);
    __syncthreads();
    unsigned* si = (unsigned*)sk;
    si[t] = myidx;
    __syncthreads();
    for (unsigned k = 2; k <= 256; k <<= 1) {
        for (unsigned j = k >> 1; j > 0; j >>= 1) {
            unsigned i = t, ixj = i ^ j;
            if (ixj > i) {
                unsigned x = si[i], y = si[ixj];
                bool up = ((i & k) == 0);
                if ((x > y) == up) { si[i] = y; si[ixj] = x; }
            }
            __syncthreads();
        }
    }
    int sel = (int)si[t];
    sel_idx[((size_t)dir * B + b) * M + t] = sel;
    nn_idx[((size_t)dir * B + b) * M + t] = (int)(unsigned)(rk[sel] & 0xFFFFFFFFull);
}

// ---------------------------------------------------------------------------
// fp8 VICReg per (pair p, location mloc): HALF the gather bytes (the measured
// limiter: 62MB compulsory random-granule HBM misses at ~640GB/s).
// 4 waves, 4 chunks (128 cols = 128B) resident: X 32KB + Y 32KB + colpart
// 8KB -> 2 blocks/CU. Grams via mfma_f32_16x16x32_fp8_fp8 (identical A/B
// lane addressing => within-k permutation cancels). 16B-granule XOR swizzle
// on src+read (rule 21). Fused finalize via completion counter acc[6].
// ---------------------------------------------------------------------------
__global__ __launch_bounds__(256, 2) void vicreg_fp8_kernel(
    const u8* __restrict__ a8, const u8* __restrict__ b8,
    const int* __restrict__ sel_idx, const int* __restrict__ nn_idx,
    float* __restrict__ acc, float* __restrict__ outp) {
    const int mloc = blockIdx.x;
    const int p = blockIdx.y;
    const int t = threadIdx.x;
    const int l = t & 63, w = t >> 6;

    __shared__ __align__(16) u8 X8[4][64 * 128];    // 32 KB
    __shared__ __align__(16) u8 Y8[4][64 * 128];    // 32 KB
    __shared__ float colpart[4][4][128];            // [wave][stat][col] 8 KB
    __shared__ float Rsx[64], Rsy[64];
    __shared__ int xi[64], yi[64];
    __shared__ float redsc[4][4];

    if (t < 64) xi[t] = sel_idx[((size_t)p * B + t) * M + mloc];
    else if (t < 128) yi[t - 64] = nn_idx[((size_t)p * B + (t - 64)) * M + mloc];
    __syncthreads();

    const u8* Xg = (p & 1) ? b8 : a8;
    const u8* Yg = (p & 1) ? a8 : b8;
    size_t xofs[2], yofs[2];
    int ldst[2];
#pragma unroll
    for (int s = 0; s < 2; ++s) {
        int r = w * 16 + s * 8 + (l >> 3);           // local row = batch index
        int sg = (l & 7) ^ (r & 7);                  // pre-swizzled src granule
        xofs[s] = ((size_t)(r * N + xi[r])) * C + sg * 16;
        yofs[s] = ((size_t)(r * N + yi[r])) * C + sg * 16;
        ldst[s] = (w * 16 + s * 8) * 128;
    }

    // stage all 4 chunks (16 gload/wave), drain once
#pragma unroll
    for (int kc = 0; kc < 4; ++kc)
#pragma unroll
        for (int s = 0; s < 2; ++s) {
            gload_lds16b(Xg + xofs[s] + kc * 128, &X8[kc][ldst[s]]);
            gload_lds16b(Yg + yofs[s] + kc * 128, &Y8[kc][ldst[s]]);
        }
    __syncthreads();

    f32x4 Gx[4], Gy[4], Z;
#pragma unroll
    for (int j = 0; j < 4; ++j) { Gx[j] = (f32x4){0,0,0,0}; Gy[j] = (f32x4){0,0,0,0}; }
    Z = (f32x4){0, 0, 0, 0};
    float stdacc = 0.f, covdacc = 0.f, reprp = 0.f;

    const int hh = (l >> 4) >> 1;
    const int wi = ((l >> 4) & 1) << 3;

#pragma unroll
    for (int kc = 0; kc < 4; ++kc) {
        const u8* Xc = X8[kc];
        const u8* Yc = Y8[kc];

        // ---- MFMA Grams: 4 K=32 steps cover this 128-col chunk ----
#pragma unroll
        for (int ks = 0; ks < 4; ++ks) {
            int soff = ((((ks << 1) | hh) ^ (l & 7)) << 4) + wi;   // row&7==l&7
            int ra = (w << 4) + (l & 15);
            i64 ax = *(const i64*)&Xc[ra * 128 + soff];
            i64 ay = *(const i64*)&Yc[ra * 128 + soff];
            i64 bx[4], by[4];
#pragma unroll
            for (int j = 0; j < 4; ++j) {
                int rb = (j << 4) + (l & 15);
                bx[j] = *(const i64*)&Xc[rb * 128 + soff];
                by[j] = *(const i64*)&Yc[rb * 128 + soff];
            }
#pragma unroll
            for (int j = 0; j < 4; ++j) {
                Gx[j] = __builtin_amdgcn_mfma_f32_16x16x32_fp8_fp8(ax, bx[j], Gx[j], 0, 0, 0);
                Gy[j] = __builtin_amdgcn_mfma_f32_16x16x32_fp8_fp8(ay, by[j], Gy[j], 0, 0, 0);
            }
            Z = __builtin_amdgcn_mfma_f32_16x16x32_fp8_fp8(ax, ay, Z, 0, 0, 0);
        }

        // ---- column stats: 4 byte-cols/thread, 8 rows, fp32 accum ----
        {
            int c4 = (l & 31) << 2;
            int g2 = (w << 1) + (l >> 5);
            float s1x0 = 0, s1x1 = 0, s1x2 = 0, s1x3 = 0;
            float s2x0 = 0, s2x1 = 0, s2x2 = 0, s2x3 = 0;
            float s1y0 = 0, s1y1 = 0, s1y2 = 0, s1y3 = 0;
            float s2y0 = 0, s2y1 = 0, s2y2 = 0, s2y3 = 0;
#pragma unroll
            for (int rr = 0; rr < 8; ++rr) {
                int r = g2 * 8 + rr;
                int off = r * 128 + (((c4 >> 4) ^ (r & 7)) << 4) + (c4 & 15);
                unsigned wx = *(const unsigned*)&Xc[off];
                unsigned wy = *(const unsigned*)&Yc[off];
                float x0 = __builtin_amdgcn_cvt_f32_fp8(wx, 0);
                float x1 = __builtin_amdgcn_cvt_f32_fp8(wx, 1);
                float x2 = __builtin_amdgcn_cvt_f32_fp8(wx, 2);
                float x3 = __builtin_amdgcn_cvt_f32_fp8(wx, 3);
                float y0 = __builtin_amdgcn_cvt_f32_fp8(wy, 0);
                float y1 = __builtin_amdgcn_cvt_f32_fp8(wy, 1);
                float y2 = __builtin_amdgcn_cvt_f32_fp8(wy, 2);
                float y3 = __builtin_amdgcn_cvt_f32_fp8(wy, 3);
                s1x0 += x0; s1x1 += x1; s1x2 += x2; s1x3 += x3;
                s2x0 = fmaf(x0, x0, s2x0); s2x1 = fmaf(x1, x1, s2x1);
                s2x2 = fmaf(x2, x2, s2x2); s2x3 = fmaf(x3, x3, s2x3);
                s1y0 += y0; s1y1 += y1; s1y2 += y2; s1y3 += y3;
                s2y0 = fmaf(y0, y0, s2y0); s2y1 = fmaf(y1, y1, s2y1);
                s2y2 = fmaf(y2, y2, s2y2); s2y3 = fmaf(y3, y3, s2y3);
            }
            s1x0 += __shfl_xor(s1x0, 32, 64); s1x1 += __shfl_xor(s1x1, 32, 64);
            s1x2 += __shfl_xor(s1x2, 32, 64); s1x3 += __shfl_xor(s1x3, 32, 64);
            s2x0 += __shfl_xor(s2x0, 32, 64); s2x1 += __shfl_xor(s2x1, 32, 64);
            s2x2 += __shfl_xor(s2x2, 32, 64); s2x3 += __shfl_xor(s2x3, 32, 64);
            s1y0 += __shfl_xor(s1y0, 32, 64); s1y1 += __shfl_xor(s1y1, 32, 64);
            s1y2 += __shfl_xor(s1y2, 32, 64); s1y3 += __shfl_xor(s1y3, 32, 64);
            s2y0 += __shfl_xor(s2y0, 32, 64); s2y1 += __shfl_xor(s2y1, 32, 64);
            s2y2 += __shfl_xor(s2y2, 32, 64); s2y3 += __shfl_xor(s2y3, 32, 64);
            if (l < 32) {
                *(float4*)&colpart[w][0][c4] = make_float4(s1x0, s1x1, s1x2, s1x3);
                *(float4*)&colpart[w][1][c4] = make_float4(s2x0, s2x1, s2x2, s2x3);
                *(float4*)&colpart[w][2][c4] = make_float4(s1y0, s1y1, s1y2, s1y3);
                *(float4*)&colpart[w][3][c4] = make_float4(s2y0, s2y1, s2y2, s2y3);
            }
        }
        __syncthreads();   // stats of chunk kc visible

        if (t < 128) {
            float s1x = 0, s2x = 0, s1y = 0, s2y = 0;
#pragma unroll
            for (int ww = 0; ww < 4; ++ww) {
                s1x += colpart[ww][0][t]; s2x += colpart[ww][1][t];
                s1y += colpart[ww][2][t]; s2y += colpart[ww][3][t];
            }
            float sx = s2x - s1x * s1x * (1.f / 64.f);
            float sy = s2y - s1y * s1y * (1.f / 64.f);
            stdacc += fmaxf(0.f, 1.f - sqrtf(sx * (1.f / 63.f) + 1e-4f)) +
                      fmaxf(0.f, 1.f - sqrtf(sy * (1.f / 63.f) + 1e-4f));
            covdacc += sx * sx + sy * sy;
            reprp += s2x + s2y;
        }
        __syncthreads();   // WAR: colpart reads done before next chunk writes
    }

    // ---- epilogue ----
    float zd = 0.f;
    {
        int rbase = (l >> 4) << 2, col = l & 15;
#pragma unroll
        for (int reg = 0; reg < 4; ++reg)
            zd += (col == rbase + reg) ? Z[reg] : 0.f;
    }
    float rsx[4], rsy[4];
#pragma unroll
    for (int reg = 0; reg < 4; ++reg) {
        rsx[reg] = Gx[0][reg] + Gx[1][reg] + Gx[2][reg] + Gx[3][reg];
        rsy[reg] = Gy[0][reg] + Gy[1][reg] + Gy[2][reg] + Gy[3][reg];
    }
#pragma unroll
    for (int off = 1; off < 16; off <<= 1)
#pragma unroll
        for (int reg = 0; reg < 4; ++reg) {
            rsx[reg] += __shfl_xor(rsx[reg], off, 64);
            rsy[reg] += __shfl_xor(rsy[reg], off, 64);
        }
    if ((l & 15) == 0) {
#pragma unroll
        for (int reg = 0; reg < 4; ++reg) {
            Rsx[(w << 4) + ((l >> 4) << 2) + reg] = rsx[reg];
            Rsy[(w << 4) + ((l >> 4) << 2) + reg] = rsy[reg];
        }
    }
    __syncthreads();
    float myx = Rsx[l], myy = Rsy[l];
#pragma unroll
    for (int off = 1; off < 64; off <<= 1) {
        myx += __shfl_xor(myx, off, 64);
        myy += __shfl_xor(myy, off, 64);
    }
    float tX = myx * (1.f / 4096.f), tY = myy * (1.f / 4096.f);
    float kn = 0.f;
#pragma unroll
    for (int j = 0; j < 4; ++j) {
        float cX = Rsx[(j << 4) + (l & 15)] * (1.f / 64.f);
        float cY = Rsy[(j << 4) + (l & 15)] * (1.f / 64.f);
#pragma unroll
        for (int reg = 0; reg < 4; ++reg) {
            float K1 = Gx[j][reg] - rsx[reg] * (1.f / 64.f) - cX + tX;
            kn = fmaf(K1, K1, kn);
            float K2 = Gy[j][reg] - rsy[reg] * (1.f / 64.f) - cY + tY;
            kn = fmaf(K2, K2, kn);
        }
    }

    float v0 = reprp - 2.f * zd, v1 = stdacc, v2 = covdacc, v3 = kn;
#pragma unroll
    for (int off = 1; off < 64; off <<= 1) {
        v0 += __shfl_xor(v0, off, 64);
        v1 += __shfl_xor(v1, off, 64);
        v2 += __shfl_xor(v2, off, 64);
        v3 += __shfl_xor(v3, off, 64);
    }
    if (l == 0) { redsc[w][0] = v0; redsc[w][1] = v1; redsc[w][2] = v2; redsc[w][3] = v3; }
    __syncthreads();
    if (t == 0) {
        float r0 = 0, r1 = 0, r2 = 0, r3 = 0;
#pragma unroll
        for (int ww = 0; ww < 4; ++ww) {
            r0 += redsc[ww][0]; r1 += redsc[ww][1];
            r2 += redsc[ww][2]; r3 += redsc[ww][3];
        }
        atomicAdd(&acc[0], r0);
        atomicAdd(&acc[1], r1);
        atomicAdd(&acc[2], r3 - r2);
        __threadfence();
        unsigned old = atomicAdd((unsigned*)&acc[6], 1u);
        if (old == 4 * M - 1) {
            float a0 = atomicAdd(&acc[0], 0.f);
            float a1 = atomicAdd(&acc[1], 0.f);
            float a2 = atomicAdd(&acc[2], 0.f);
            float repr = 25.f * a0 / ((float)B * (float)M * (float)C);
            float stdl = 12.5f * a1 / ((float)M * (float)C);
            float cov = a2 / (63.f * 63.f * (float)C * 2.f) / (float)M;
            outp[0] = repr + stdl + cov;
        }
    }
}

// ---------------------------------------------------------------------------
// FALLBACK fp32 path kernels (only if ws can't hold the fp8 copies)
// ---------------------------------------------------------------------------
__global__ __launch_bounds__(256) void init_kernel(u64* rowkey, float* acc) {
    int i = blockIdx.x * 256 + threadIdx.x;
    if (i < 4 * B * N) rowkey[i] = ~0ull;
    if (i < 8) acc[i] = 0.f;
}

__global__ __launch_bounds__(256) void norms_kernel(const float* __restrict__ m1,
                                                    const float* __restrict__ m2,
                                                    float* __restrict__ nrm) {
    int w = blockIdx.x * 4 + (threadIdx.x >> 6);
    int lane = threadIdx.x & 63;
    if (w >= 2 * B * N) return;
    const float* src = (w < B * N) ? m1 : m2;
    int row = (w < B * N) ? w : w - B * N;
    const float4* p = (const float4*)(src + (size_t)row * C);
    float s = 0.f;
#pragma unroll
    for (int i = 0; i < 2; ++i) {
        float4 v = p[lane + i * 64];
        s += v.x * v.x + v.y * v.y + v.z * v.z + v.w * v.w;
    }
#pragma unroll
    for (int off = 32; off > 0; off >>= 1) s += __shfl_down(s, off, 64);
    if (lane == 0) nrm[w] = s;
}

__global__ __launch_bounds__(256) void feat_dist_kernel(
    const float* __restrict__ m1, const float* __restrict__ m2,
    const float* __restrict__ nrm, u64* __restrict__ rowkey) {
    const int b = blockIdx.z;
    const int tn = blockIdx.x, tm = blockIdx.y;
    __shared__ float As[64][68];
    __shared__ float Bt[64][68];
    __shared__ u64 red[64][16];
    const int t = threadIdx.x;
    const int ty = t >> 4, tx = t & 15;
    float acc[4][4] = {};
    const float* A = m1 + (size_t)b * N * C;
    const float* Bm = m2 + (size_t)b * N * C;

    for (int k0 = 0; k0 < C; k0 += 64) {
#pragma unroll
        for (int it = 0; it < 4; ++it) {
            int idx = t + it * 256;
            int r = idx >> 4, cc = (idx & 15) << 2;
            int n = tn * 64 + r;
            float4 v = make_float4(0.f, 0.f, 0.f, 0.f);
            if (n < N) v = *(const float4*)(A + (size_t)n * C + k0 + cc);
            *(float4*)&As[r][cc] = v;
            int mm = tm * 64 + r;
            float4 w = make_float4(0.f, 0.f, 0.f, 0.f);
            if (mm < N) w = *(const float4*)(Bm + (size_t)mm * C + k0 + cc);
            Bt[cc + 0][r] = w.x; Bt[cc + 1][r] = w.y;
            Bt[cc + 2][r] = w.z; Bt[cc + 3][r] = w.w;
        }
        __syncthreads();
#pragma unroll 4
        for (int kq = 0; kq < 64; kq += 4) {
            float aa[4][4], bb[4][4];
#pragma unroll
            for (int i = 0; i < 4; ++i) {
                float4 v = *(const float4*)&As[ty * 4 + i][kq];
                aa[i][0] = v.x; aa[i][1] = v.y; aa[i][2] = v.z; aa[i][3] = v.w;
            }
#pragma unroll
            for (int qq = 0; qq < 4; ++qq) {
                float4 v = *(const float4*)&Bt[kq + qq][tx * 4];
                bb[qq][0] = v.x; bb[qq][1] = v.y; bb[qq][2] = v.z; bb[qq][3] = v.w;
            }
#pragma unroll
            for (int qq = 0; qq < 4; ++qq)
#pragma unroll
                for (int i = 0; i < 4; ++i)
#pragma unroll
                    for (int j = 0; j < 4; ++j)
                        acc[i][j] = fmaf(aa[i][qq], bb[qq][j], acc[i][j]);
        }
        __syncthreads();
    }

    u64 rk[4] = {~0ull, ~0ull, ~0ull, ~0ull};
    u64 ck[4] = {~0ull, ~0ull, ~0ull, ~0ull};
    const float* nr1 = nrm;
    const float* nr2 = nrm + B * N;
#pragma unroll
    for (int i = 0; i < 4; ++i) {
        int n = tn * 64 + ty * 4 + i;
        if (n >= N) continue;
        float a2 = nr1[b * N + n];
#pragma unroll
        for (int j = 0; j < 4; ++j) {
            int mm = tm * 64 + tx * 4 + j;
            if (mm >= N) continue;
            float b2 = nr2[b * N + mm];
            float d2 = a2 + b2 - 2.f * acc[i][j];
            unsigned vb = __float_as_uint(fmaxf(d2, 0.f));
            u64 kv = ((u64)vb << 32);
            rk[i] = umin64(rk[i], kv | (unsigned)mm);
            ck[j] = umin64(ck[j], kv | (unsigned)n);
        }
    }
#pragma unroll
    for (int i = 0; i < 4; ++i) red[ty * 4 + i][tx] = rk[i];
    __syncthreads();
    if (t < 64) {
        u64 best = red[t][0];
#pragma unroll
        for (int x = 1; x < 16; ++x) best = umin64(best, red[t][x]);
        int n = tn * 64 + t;
        if (n < N && best != ~0ull)
            atomicMin(&rowkey[(size_t)b * N + n], best);
    }
    __syncthreads();
#pragma unroll
    for (int j = 0; j < 4; ++j) red[tx * 4 + j][ty] = ck[j];
    __syncthreads();
    if (t < 64) {
        u64 best = red[t][0];
#pragma unroll
        for (int x = 1; x < 16; ++x) best = umin64(best, red[t][x]);
        int mm = tm * 64 + t;
        if (mm < N && best != ~0ull)
            atomicMin(&rowkey[(size_t)B * N + (size_t)b * N + mm], best);
    }
}

__device__ __forceinline__ float blockReduce(float v, float* redb, int t) {
    __syncthreads();
    redb[t] = v;
    __syncthreads();
    for (int s = 128; s > 0; s >>= 1) {
        if (t < s) redb[t] += redb[t + s];
        __syncthreads();
    }
    return redb[0];
}

__global__ __launch_bounds__(256) void vicreg_kernel(
    const float* __restrict__ m1, const float* __restrict__ m2,
    const int* __restrict__ sel_idx, const int* __restrict__ nn_idx,
    float* __restrict__ acc) {
    const int mloc = blockIdx.x;
    const int p = blockIdx.y;
    const int t = threadIdx.x;
    const float* X = (p & 1) ? m2 : m1;
    const float* Y = (p & 1) ? m1 : m2;
    __shared__ float Xs[64][65];
    __shared__ float Ys[64][65];
    __shared__ int xi[64], yi[64];
    __shared__ float pst[192][5];
    __shared__ float Rs[64];
    __shared__ float Tsh;
    __shared__ float redb[256];

    if (t < 64) {
        xi[t] = sel_idx[((size_t)p * B + t) * M + mloc];
        yi[t] = nn_idx[((size_t)p * B + t) * M + mloc];
    }
    __syncthreads();

    float Gx[4][4] = {}, Gy[4][4] = {};
    float stdx = 0, stdy = 0, covdx = 0, covdy = 0, repr = 0;
    const int i0 = (t >> 4) << 2, j0 = (t & 15) << 2;

    for (int c0 = 0; c0 < C; c0 += 64) {
#pragma unroll
        for (int it = 0; it < 4; ++it) {
            int fidx = t + it * 256;
            int r = fidx >> 4, cc = (fidx & 15) << 2;
            float4 v = *(const float4*)(X + ((size_t)r * N + xi[r]) * C + c0 + cc);
            Xs[r][cc] = v.x; Xs[r][cc + 1] = v.y; Xs[r][cc + 2] = v.z; Xs[r][cc + 3] = v.w;
            float4 w = *(const float4*)(Y + ((size_t)r * N + yi[r]) * C + c0 + cc);
            Ys[r][cc] = w.x; Ys[r][cc + 1] = w.y; Ys[r][cc + 2] = w.z; Ys[r][cc + 3] = w.w;
        }
        __syncthreads();
#pragma unroll 4
        for (int k = 0; k < 64; ++k) {
            float ax[4], bx[4], ay[4], by[4];
#pragma unroll
            for (int i = 0; i < 4; ++i) { ax[i] = Xs[i0 + i][k]; ay[i] = Ys[i0 + i][k]; }
#pragma unroll
            for (int j = 0; j < 4; ++j) { bx[j] = Xs[j0 + j][k]; by[j] = Ys[j0 + j][k]; }
#pragma unroll
            for (int i = 0; i < 4; ++i)
#pragma unroll
                for (int j = 0; j < 4; ++j) {
                    Gx[i][j] = fmaf(ax[i], bx[j], Gx[i][j]);
                    Gy[i][j] = fmaf(ay[i], by[j], Gy[i][j]);
                }
        }
        {
            float s1x = 0, s2x = 0, s1y = 0, s2y = 0, sxy = 0;
            int col = t & 63, g = t >> 6;
            for (int r = g * 16; r < g * 16 + 16; ++r) {
                float xv = Xs[r][col], yv = Ys[r][col];
                s1x += xv; s2x += xv * xv;
                s1y += yv; s2y += yv * yv;
                sxy += xv * yv;
            }
            if (g) {
                float* qq = pst[(g - 1) * 64 + col];
                qq[0] = s1x; qq[1] = s2x; qq[2] = s1y; qq[3] = s2y; qq[4] = sxy;
            }
            __syncthreads();
            if (g == 0) {
#pragma unroll
                for (int gg = 0; gg < 3; ++gg) {
                    float* qq = pst[gg * 64 + col];
                    s1x += qq[0]; s2x += qq[1]; s1y += qq[2]; s2y += qq[3]; sxy += qq[4];
                }
                float xb = s1x * (1.f / 64.f);
                float sx = s2x - 64.f * xb * xb;
                float yb = s1y * (1.f / 64.f);
                float sy = s2y - 64.f * yb * yb;
                stdx += fmaxf(0.f, 1.f - sqrtf(sx * (1.f / 63.f) + 1e-4f));
                stdy += fmaxf(0.f, 1.f - sqrtf(sy * (1.f / 63.f) + 1e-4f));
                covdx += sx * sx;
                covdy += sy * sy;
                repr += s2x + s2y - 2.f * sxy;
            }
            __syncthreads();
        }
    }

    float knx = 0.f, kny = 0.f;
    float (*Gs)[65] = (float(*)[65]) & Xs[0][0];
    __syncthreads();
#pragma unroll
    for (int i = 0; i < 4; ++i)
#pragma unroll
        for (int j = 0; j < 4; ++j) Gs[i0 + i][j0 + j] = Gx[i][j];
    __syncthreads();
    if (t < 64) {
        float r = 0;
        for (int j = 0; j < 64; ++j) r += Gs[t][j];
        Rs[t] = r;
    }
    __syncthreads();
    if (t < 64) {
        float r = Rs[t];
#pragma unroll
        for (int off = 32; off > 0; off >>= 1) r += __shfl_down(r, off, 64);
        if (t == 0) Tsh = r;
    }
    __syncthreads();
    {
        float T = Tsh * (1.f / 4096.f);
#pragma unroll
        for (int i = 0; i < 4; ++i)
#pragma unroll
            for (int j = 0; j < 4; ++j) {
                float Kij = Gx[i][j] - (Rs[i0 + i] + Rs[j0 + j]) * (1.f / 64.f) + T;
                knx = fmaf(Kij, Kij, knx);
            }
    }
    __syncthreads();
#pragma unroll
    for (int i = 0; i < 4; ++i)
#pragma unroll
        for (int j = 0; j < 4; ++j) Gs[i0 + i][j0 + j] = Gy[i][j];
    __syncthreads();
    if (t < 64) {
        float r = 0;
        for (int j = 0; j < 64; ++j) r += Gs[t][j];
        Rs[t] = r;
    }
    __syncthreads();
    if (t < 64) {
        float r = Rs[t];
#pragma unroll
        for (int off = 32; off > 0; off >>= 1) r += __shfl_down(r, off, 64);
        if (t == 0) Tsh = r;
    }
    __syncthreads();
    {
        float T = Tsh * (1.f / 4096.f);
#pragma unroll
        for (int i = 0; i < 4; ++i)
#pragma unroll
            for (int j = 0; j < 4; ++j) {
                float Kij = Gy[i][j] - (Rs[i0 + i] + Rs[j0 + j]) * (1.f / 64.f) + T;
                kny = fmaf(Kij, Kij, kny);
            }
    }

    float v_repr = blockReduce(repr, redb, t);
    float v_std = blockReduce(stdx + stdy, redb, t);
    float v_covd = blockReduce(covdx + covdy, redb, t);
    float v_kn = blockReduce(knx + kny, redb, t);
    if (t == 0) {
        atomicAdd(&acc[0], v_repr);
        atomicAdd(&acc[1], v_std);
        atomicAdd(&acc[2], v_kn - v_covd);
    }
}

// ---------------------------------------------------------------------------
__global__ void finalize_kernel(const float* __restrict__ acc, float* __restrict__ out) {
    if (threadIdx.x == 0 && blockIdx.x == 0) {
        float repr = 25.f * acc[0] / ((float)B * (float)M * (float)C);
        float stdl = 12.5f * acc[1] / ((float)M * (float)C);
        float cov = acc[2] / (63.f * 63.f * (float)C * 2.f) / (float)M;
        out[0] = repr + stdl + cov;
    }
}

// ---------------------------------------------------------------------------
extern "C" void kernel_launch(void* const* d_in, const int* in_sizes, int n_in,
                              void* d_out, int out_size, void* d_ws, size_t ws_size,
                              hipStream_t stream) {
    const float* m1 = (const float*)d_in[0];
    const float* m2 = (const float*)d_in[1];
    const float* l1 = (const float*)d_in[2];
    const float* l2 = (const float*)d_in[3];
    float* out = (float*)d_out;
    char* ws = (char*)d_ws;

    u64* rowkey = (u64*)ws;                                   // [4][B][N]
    size_t off = (size_t)4 * B * N * sizeof(u64);
    float* nrm = (float*)(ws + off); off += (size_t)2 * B * N * sizeof(float);
    int* sel_idx = (int*)(ws + off); off += (size_t)4 * B * M * sizeof(int);
    int* nn_idx = (int*)(ws + off);  off += (size_t)4 * B * M * sizeof(int);
    float* acc = (float*)(ws + off); off += 256;
    off = (off + 255) & ~(size_t)255;
    u8* a8 = (u8*)(ws + off);
    u8* b8 = a8 + (size_t)B * N * C;
    size_t need = off + (size_t)2 * B * N * C;   // ~54 MB total (fp8 copies)
    bool use_fp8 = ws_size >= need;              // ws_size fixed -> deterministic

    // ws is NOT re-poisoned between replays: every launch re-inits all state
    // it reads. fp8 path: convnorm clears rowkey dirs 0,1; loc_dist
    // plain-stores dirs 2,3; select zeroes acc[0..7] (incl. completion
    // counter acc[6]); vicreg finalizes out[0].
    if (use_fp8) {
        convnorm_kernel<<<dim3(2 * B * N / 4), dim3(256), 0, stream>>>(
            m1, m2, a8, b8, nrm, rowkey);
        feat_mfma_kernel<<<dim3(64 * 49), dim3(256), 0, stream>>>(a8, b8, nrm, rowkey);
        loc_dist_kernel<<<dim3((N + 255) / 256, B, 2), dim3(256), 0, stream>>>(l1, l2, rowkey);
        select_kernel<<<dim3(B, 4), dim3(256), 0, stream>>>(rowkey, sel_idx, nn_idx, acc);
        vicreg_fp8_kernel<<<dim3(M, 4), dim3(256), 0, stream>>>(
            a8, b8, sel_idx, nn_idx, acc, out);
    } else {
        init_kernel<<<dim3((4 * B * N + 255) / 256), dim3(256), 0, stream>>>(rowkey, acc);
        norms_kernel<<<dim3(2 * B * N / 4), dim3(256), 0, stream>>>(m1, m2, nrm);
        feat_dist_kernel<<<dim3(13, 13, B), dim3(256), 0, stream>>>(m1, m2, nrm, rowkey);
        loc_dist_kernel<<<dim3((N + 255) / 256, B, 2), dim3(256), 0, stream>>>(l1, l2, rowkey);
        select_kernel<<<dim3(B, 4), dim3(256), 0, stream>>>(rowkey, sel_idx, nn_idx, acc);
        vicreg_kernel<<<dim3(M, 4), dim3(256), 0, stream>>>(m1, m2, sel_idx, nn_idx, acc);
        finalize_kernel<<<dim3(1), dim3(64), 0, stream>>>(acc, out);
    }
}